// Round 4
// baseline (304.417 us; speedup 1.0000x reference)
//
#include <hip/hip_runtime.h>
#include <hip/hip_bf16.h>
#include <cstdint>

#define TOK 1024      // B*L
#define LSEQ 512
#define DMODEL 1024
#define DPROJ 6464
#define DPROJP 6528   // padded to 51*128
#define DSSM 2048
#define NHEADS 32
#define HEADDIM 64
#define DSTATE 128
#define NCH 8
#define CL 64

typedef __attribute__((ext_vector_type(4))) float f32x4;
typedef __attribute__((ext_vector_type(8))) short s16x8;
typedef __attribute__((ext_vector_type(4))) ushort u16x4;

__device__ __forceinline__ ushort f2bf(float x){
  union { float f; uint32_t u; } v; v.f = x;
  uint32_t r = (v.u + 0x7FFFu + ((v.u >> 16) & 1u)) >> 16;
  return (ushort)r;
}
__device__ __forceinline__ float bf2f(ushort h){
  union { uint32_t u; float f; } v; v.u = ((uint32_t)h) << 16;
  return v.f;
}
__device__ __forceinline__ float silu_f(float x){
  return x*__builtin_amdgcn_rcpf(1.f+__expf(-x));
}

__device__ __forceinline__ void gload16(const ushort* g, ushort* l){
  __builtin_amdgcn_global_load_lds(
      (const __attribute__((address_space(1))) unsigned int*)g,
      (__attribute__((address_space(3))) unsigned int*)l, 16, 0, 0);
}

// ------------- transpose W (K x N) -> bf16 hi/lo (Npad x K) -------------
__global__ __launch_bounds__(256) void transq_kernel(const float* __restrict__ W,
    ushort* __restrict__ Th, ushort* __restrict__ Tl, int K, int N)
{
  __shared__ float tile[32][33];
  int tx = threadIdx.x & 31, ty = threadIdx.x >> 5;
  int n = blockIdx.x*32 + tx;
  #pragma unroll
  for (int i=0;i<4;i++){
    int k = blockIdx.y*32 + ty + i*8;
    tile[ty+i*8][tx] = (n < N) ? W[(size_t)k*N + n] : 0.f;
  }
  __syncthreads();
  #pragma unroll
  for (int i=0;i<4;i++){
    int nn = blockIdx.x*32 + ty + i*8;
    int kk = blockIdx.y*32 + tx;
    float v = tile[tx][ty+i*8];
    ushort hi = f2bf(v);
    ushort lo = f2bf(v - bf2f(hi));
    Th[(size_t)nn*K + kk] = hi;
    Tl[(size_t)nn*K + kk] = lo;
  }
}

// ------------- split fp32 matrix -> bf16 hi/lo (same layout) -------------
__global__ __launch_bounds__(256) void splitA_kernel(const float* __restrict__ A,
    ushort* __restrict__ H, ushort* __restrict__ Lo)
{
  int i = blockIdx.x*256 + threadIdx.x;
  f32x4 v = ((const f32x4*)A)[i];
  u16x4 h, l;
  #pragma unroll
  for (int j=0;j<4;j++){
    ushort hh = f2bf(v[j]);
    h[j] = hh; l[j] = f2bf(v[j] - bf2f(hh));
  }
  *(u16x4*)&H[(size_t)i*4]  = h;
  *(u16x4*)&Lo[(size_t)i*4] = l;
}

// ------------- GEMM (m97-style): 128x128 tile, global_load_lds staging -------------
__global__ __launch_bounds__(256) void gemmq_kernel(
    const ushort* __restrict__ Ah, const ushort* __restrict__ Al,
    const ushort* __restrict__ Bh, const ushort* __restrict__ Bl,
    float* __restrict__ C, int K, int kLen, int ldc, int nbn, int chunk)
{
  __shared__ ushort sAh[4096], sAl[4096], sBh[4096], sBl[4096];
  int bid = blockIdx.x;
  int newL = (bid & 7)*chunk + (bid >> 3);   // XCD-chunked swizzle
  int bm = newL & 7;
  int pan = newL >> 3;
  int bn = pan % nbn;
  int z  = pan / nbn;
  int k0 = z * kLen;
  C += (size_t)z * 1024 * ldc;

  int tid = threadIdx.x;
  int wid = tid >> 6, lane = tid & 63;
  int wr = wid >> 1, wc = wid & 1;
  int fr = lane & 15, kg = lane >> 4;
  f32x4 acc[4][4] = {};

  int srow = tid & 127, skg = tid >> 7;
  const ushort* gA_h = Ah + (size_t)(bm*128+srow)*K + k0 + skg*8;
  const ushort* gA_l = Al + (size_t)(bm*128+srow)*K + k0 + skg*8;
  const ushort* gB_h = Bh + (size_t)(bn*128+srow)*K + k0 + skg*8;
  const ushort* gB_l = Bl + (size_t)(bn*128+srow)*K + k0 + skg*8;
  ushort* dA_h = sAh + tid*8;
  ushort* dA_l = sAl + tid*8;
  ushort* dB_h = sBh + tid*8;
  ushort* dB_l = sBl + tid*8;

  int rA = kg*1024 + (wr*64 + fr)*8;
  int rB = kg*1024 + (wc*64 + fr)*8;
  int NK = kLen >> 5;

  gload16(gA_h, dA_h); gload16(gA_h+16, dA_h+2048);
  gload16(gA_l, dA_l); gload16(gA_l+16, dA_l+2048);
  gload16(gB_h, dB_h); gload16(gB_h+16, dB_h+2048);
  gload16(gB_l, dB_l); gload16(gB_l+16, dB_l+2048);

  for (int ks=0; ks<NK; ks++){
    __syncthreads();
    s16x8 afh[4], afl[4], bfh[4], bfl[4];
    #pragma unroll
    for (int i=0;i<4;i++){
      afh[i] = *(const s16x8*)&sAh[rA + i*128];
      afl[i] = *(const s16x8*)&sAl[rA + i*128];
      bfh[i] = *(const s16x8*)&sBh[rB + i*128];
      bfl[i] = *(const s16x8*)&sBl[rB + i*128];
    }
    __syncthreads();
    if (ks+1 < NK){
      int off = (ks+1)*32;
      gload16(gA_h+off, dA_h); gload16(gA_h+off+16, dA_h+2048);
      gload16(gA_l+off, dA_l); gload16(gA_l+off+16, dA_l+2048);
      gload16(gB_h+off, dB_h); gload16(gB_h+off+16, dB_h+2048);
      gload16(gB_l+off, dB_l); gload16(gB_l+off+16, dB_l+2048);
    }
    #pragma unroll
    for (int i=0;i<4;i++){
      #pragma unroll
      for (int j=0;j<4;j++){
        acc[i][j] = __builtin_amdgcn_mfma_f32_16x16x32_bf16(afh[i], bfh[j], acc[i][j], 0,0,0);
        acc[i][j] = __builtin_amdgcn_mfma_f32_16x16x32_bf16(afh[i], bfl[j], acc[i][j], 0,0,0);
        acc[i][j] = __builtin_amdgcn_mfma_f32_16x16x32_bf16(afl[i], bfh[j], acc[i][j], 0,0,0);
      }
    }
  }
  int rq = kg * 4;
  #pragma unroll
  for (int i=0;i<4;i++){
    #pragma unroll
    for (int j=0;j<4;j++){
      int row = bm*128 + wr*64 + i*16 + rq;
      int col = bn*128 + wc*64 + j*16 + fr;
      #pragma unroll
      for (int q=0;q<4;q++)
        C[(size_t)(row+q)*ldc + col] = acc[i][j][q];
    }
  }
}

// ------------- reduce 4 split-K partials -------------
__global__ __launch_bounds__(256) void red4_kernel(const float* __restrict__ P, float* __restrict__ O){
  int i = blockIdx.x*256 + threadIdx.x;
  f32x4 v = ((const f32x4*)P)[i];
  v += ((const f32x4*)P)[i + 262144];
  v += ((const f32x4*)P)[i + 2*262144];
  v += ((const f32x4*)P)[i + 3*262144];
  ((f32x4*)O)[i] = v;
}

// ------------- cumsum(theta) + mean-over-heads cos/sin -------------
__global__ __launch_bounds__(512) void cum2_kernel(const float* __restrict__ zx,
    float* __restrict__ cosm, float* __restrict__ sinm)
{
  __shared__ float wsum[8];
  int b = blockIdx.x >> 6, hd = blockIdx.x & 63;
  int l = threadIdx.x, lane = l & 63, w = l >> 6;
  float accc = 0.f, accs = 0.f;
  const float* base = zx + (size_t)(b*LSEQ)*DPROJP + 4416 + hd;
  for (int h = 0; h < 32; h++){
    float x = base[(size_t)l*DPROJP + h*64];
    #pragma unroll
    for (int m=1; m<64; m<<=1){
      float v = __shfl_up(x, m, 64);
      if (lane >= m) x += v;
    }
    if (lane == 63) wsum[w] = x;
    __syncthreads();
    float pre = 0.f;
    for (int i=0;i<w;i++) pre += wsum[i];
    x += pre;
    float s, c;
    __sincosf(x, &s, &c);
    accc += c; accs += s;
    __syncthreads();
  }
  int t = b*LSEQ + l;
  cosm[t*64+hd] = accc*(1.f/32.f);
  sinm[t*64+hd] = accs*(1.f/32.f);
}

// ------------- per-token: B/C rms+rope, dt/dA/lam/lamg pack -------------
__global__ __launch_bounds__(256) void ew_kernel(const float* __restrict__ zx,
    const float* __restrict__ cosm, const float* __restrict__ sinm,
    const float* __restrict__ dt_bias, const float* __restrict__ A_log,
    const float* __restrict__ B_bias, const float* __restrict__ C_bias,
    const float* __restrict__ Bnw, const float* __restrict__ Cnw,
    float* __restrict__ Bg, float* __restrict__ Cg, float4* __restrict__ scal)
{
  int t = blockIdx.x; int tid = threadIdx.x;
  __shared__ float red[256];
  __shared__ float nb[128], nc[128];
  const float* row = zx + (size_t)t*DPROJP;
  float v;
  if (tid < 128) v = row[4096 + tid] + B_bias[tid];
  else           v = row[4224 + (tid-128)] + C_bias[tid-128];
  red[tid] = v*v;
  __syncthreads();
  #pragma unroll
  for (int s=64; s>0; s>>=1){
    if ((tid & 127) < s) red[tid] += red[tid + s];
    __syncthreads();
  }
  float ms = red[(tid < 128) ? 0 : 128] * (1.f/128.f);
  float rs = rsqrtf(ms + 1e-5f);
  float w  = (tid < 128) ? Bnw[tid] : Cnw[tid-128];
  float nv = v * rs * w;
  if (tid < 128) nb[tid] = nv; else nc[tid-128] = nv;
  __syncthreads();
  if (tid < 64){
    float c = cosm[t*64+tid], s = sinm[t*64+tid];
    float a = nb[tid], bq = nb[tid+64];
    Bg[(size_t)t*128 + tid]      = a*c - bq*s;
    Bg[(size_t)t*128 + 64 + tid] = bq*c + a*s;
  } else if (tid < 128){
    int i = tid - 64;
    float c = cosm[t*64+i], s = sinm[t*64+i];
    float a = nc[i], bq = nc[i+64];
    Cg[(size_t)t*128 + i]      = a*c - bq*s;
    Cg[(size_t)t*128 + 64 + i] = bq*c + a*s;
  } else if (tid < 160){
    int hh = tid - 128;
    float dtr = row[4352 + hh] + dt_bias[hh];
    float dtv = (dtr > 20.f) ? dtr : log1pf(expf(dtr));
    float dA  = expf(-dtv * expf(A_log[hh]));
    float lr  = row[4384 + hh];
    float lam = 1.f/(1.f + expf(-lr));
    float lg = lam;
    #pragma unroll
    for (int m=1;m<32;m<<=1) lg += __shfl_xor(lg, m, 64);
    lg *= (1.f/32.f);
    scal[(size_t)t*32 + hh] = make_float4(dtv, dA, lam, lg);
  }
}

// ------------- pack xe (silu + lambda mix), chunk-transposed [b][c][h][p][t] -------------
__global__ __launch_bounds__(256) void packx_kernel(const float* __restrict__ zx,
    const float4* __restrict__ scal, float* __restrict__ xe)
{
  int blk = blockIdx.x;                 // ((b*8+c)*32+h)
  int h = blk & 31, c = (blk >> 5) & 7, b = blk >> 8;
  int tid = threadIdx.x;
  int p = tid >> 2, t4 = (tid & 3) * 16;
  int t0 = b*LSEQ + c*CL;
  const float* xsrc = zx + (size_t)t0*DPROJP + 2048 + h*64 + p;
  float o[16];
  float xsprev;
  {
    int tg = t0 + t4;
    xsprev = (tg > b*LSEQ) ? silu_f(xsrc[(size_t)(t4-1)*DPROJP]) : 0.f;
  }
  #pragma unroll
  for (int i=0;i<16;i++){
    int ts = t4 + i;
    float xs = silu_f(xsrc[(size_t)ts*DPROJP]);
    float lam = scal[(size_t)(t0+ts)*32 + h].z;
    o[i] = xsprev + lam*(xs - xsprev);
    xsprev = xs;
  }
  float* dst = xe + ((size_t)blk*64 + p)*64 + t4;
  #pragma unroll
  for (int i=0;i<4;i++)
    *(f32x4*)(dst + i*4) = (f32x4){o[i*4],o[i*4+1],o[i*4+2],o[i*4+3]};
}

// ------------- Beff = lamg-mixed B, layout [b][h][t][d] -------------
__global__ __launch_bounds__(128) void beff_kernel(const float* __restrict__ Bg,
    const float4* __restrict__ scal, float* __restrict__ Beff)
{
  int t = blockIdx.x;                   // global token
  int d = threadIdx.x;                  // 128
  int b = t >> 9;
  int tl = t - b*LSEQ;
  float bc = Bg[(size_t)t*128 + d];
  float bp = (tl > 0) ? Bg[(size_t)(t-1)*128 + d] : 0.f;
  #pragma unroll 4
  for (int h=0; h<32; h++){
    float lg = scal[(size_t)t*32 + h].w;
    Beff[((size_t)(b*32+h)*LSEQ + tl)*128 + d] = bp + lg*(bc - bp);
  }
}

// ------------- pack dt/dA per-chunk vectors + inclusive prefix product -------------
__global__ __launch_bounds__(256) void packs_kernel(const float4* __restrict__ scal,
    float* __restrict__ pdt, float* __restrict__ padA, float* __restrict__ prefA)
{
  int idx = blockIdx.x*256 + threadIdx.x;   // 512 = ((b*8+c)*32+h)
  int h = idx & 31, c = (idx >> 5) & 7, b = idx >> 8;
  int t0 = b*LSEQ + c*CL;
  float pref = 1.f;
  for (int ts=0; ts<CL; ts++){
    float4 sc = scal[(size_t)(t0+ts)*32 + h];
    pdt[(size_t)idx*64 + ts]  = sc.x;
    padA[(size_t)idx*64 + ts] = sc.y;
    pref *= sc.y;
    prefA[(size_t)(t0+ts)*32 + h] = pref;
  }
}

// ------------- chunked scan, pass 1 (lean inner loop) -------------
__global__ __launch_bounds__(256) void scan1_kernel(
    const float* __restrict__ xe, const float* __restrict__ Beff,
    const float* __restrict__ Cg, const float* __restrict__ pdt,
    const float* __restrict__ padA, const float* __restrict__ Dp,
    float* __restrict__ ypart, float* __restrict__ hcarry)
{
  int blk = blockIdx.x;            // ((b*32+h)*4+dq)*8+c
  int c = blk & 7, dq = (blk>>3)&3, h = (blk>>5)&31, b = blk>>10;
  int tid = threadIdx.x;
  int p = tid >> 2, ds = tid & 3;
  int d0 = dq*32 + ds*8;
  int t0 = b*LSEQ + c*CL;
  int tl0 = c*CL;
  float hreg[8] = {0,0,0,0,0,0,0,0};
  float Dh = Dp[h];
  int bch = (b*8 + c)*32 + h;
  const float* Bp  = Beff + ((size_t)(b*32+h)*LSEQ + tl0)*128 + d0;
  const float* Cp  = Cg + (size_t)t0*128 + d0;
  const float* xp  = xe + ((size_t)bch*64 + p)*64;
  const float* dtp = pdt + (size_t)bch*64;
  const float* dAp = padA + (size_t)bch*64;
  float* yp = ypart + (size_t)(dq*TOK + t0)*DSSM + h*64 + p;
  bool wy = (ds == 0);
  #pragma unroll 1
  for (int g=0; g<16; g++){
    f32x4 xev = *(const f32x4*)xp;  xp  += 4;
    f32x4 dtv = *(const f32x4*)dtp; dtp += 4;
    f32x4 dAv = *(const f32x4*)dAp; dAp += 4;
    #pragma unroll
    for (int k=0;k<4;k++){
      f32x4 b0 = *(const f32x4*)(Bp + k*128);
      f32x4 b1 = *(const f32x4*)(Bp + k*128 + 4);
      f32x4 c0 = *(const f32x4*)(Cp + k*128);
      f32x4 c1 = *(const f32x4*)(Cp + k*128 + 4);
      float bcv[8] = {b0.x,b0.y,b0.z,b0.w,b1.x,b1.y,b1.z,b1.w};
      float ccv[8] = {c0.x,c0.y,c0.z,c0.w,c1.x,c1.y,c1.z,c1.w};
      float dtx = dtv[k]*xev[k];
      float dA  = dAv[k];
      float y = 0.f;
      #pragma unroll
      for (int j=0;j<8;j++){
        hreg[j] = dA*hreg[j] + dtx*bcv[j];
        y += hreg[j]*ccv[j];
      }
      y += __shfl_xor(y, 1, 64);
      y += __shfl_xor(y, 2, 64);
      if (wy){
        if (dq == 0) y += Dh*xev[k];
        *yp = y;
      }
      yp += DSSM;
    }
    Bp += 512; Cp += 512;
  }
  float* hc = hcarry + ((((size_t)(b*32+h)*8 + c)*64 + p)*128 + d0);
  #pragma unroll
  for (int j=0;j<8;j++) hc[j] = hreg[j];
}

// ------------- pass 2: propagate carries -------------
__global__ __launch_bounds__(256) void scan2_kernel(float* __restrict__ hcarry,
    const float* __restrict__ prefA)
{
  int idx = blockIdx.x*256 + threadIdx.x;
  int d = idx & 127, pp = (idx >> 7) & 63, h = (idx >> 13) & 31, b = idx >> 18;
  size_t base = ((size_t)(b*32+h)*512 + pp)*128 + d;
  float Hin = 0.f;
  #pragma unroll
  for (int c=0; c<NCH; c++){
    float Atot = prefA[(size_t)(b*LSEQ + c*CL + CL-1)*32 + h];
    float S = hcarry[base + (size_t)c*8192];
    hcarry[base + (size_t)c*8192] = Hin;
    Hin = Atot*Hin + S;
  }
}

// ------------- pass 3: y correction -------------
__global__ __launch_bounds__(256) void scan3_kernel(const float* __restrict__ Cg,
    const float* __restrict__ hcarry, const float* __restrict__ prefA,
    float* __restrict__ ypart)
{
  __shared__ float Ct[CL*128];
  __shared__ float pf[CL];
  int blk = blockIdx.x;
  int c = blk & 7, h = (blk>>3)&31, b = blk>>8;
  int tid = threadIdx.x, p = tid >> 2, ds = tid & 3;
  int t0 = b*LSEQ + c*CL;
  float hin[32];
  const float* hp = hcarry + ((((size_t)(b*32+h)*8 + c)*64 + p)*128 + ds*32);
  #pragma unroll
  for (int k=0;k<32;k+=4){
    f32x4 v = *(const f32x4*)(hp+k);
    hin[k]=v.x; hin[k+1]=v.y; hin[k+2]=v.z; hin[k+3]=v.w;
  }
  const float4* src = (const float4*)(Cg + (size_t)t0*128);
  #pragma unroll
  for (int i=0;i<8;i++) ((float4*)Ct)[tid + i*256] = src[tid + i*256];
  if (tid < CL) pf[tid] = prefA[(size_t)(t0+tid)*32 + h];
  __syncthreads();
  float* yo = ypart + (size_t)(4*TOK + t0)*DSSM + h*64 + p;
  for (int tt=0; tt<CL; tt++){
    const float* cp = &Ct[tt*128 + ds*32];
    float dot = 0.f;
    #pragma unroll
    for (int k=0;k<32;k++) dot += cp[k]*hin[k];
    dot += __shfl_xor(dot, 1, 64);
    dot += __shfl_xor(dot, 2, 64);
    if (ds == 0) yo[(size_t)tt*DSSM] = pf[tt]*dot;
  }
}

// ------------- final: sum 5 d-partials, *silu(z), rms*norm_w -> bf16 hi/lo -------------
__global__ __launch_bounds__(256) void fin_kernel(const float* __restrict__ zx,
    const float* __restrict__ ypart, const float* __restrict__ normw,
    ushort* __restrict__ yfh, ushort* __restrict__ yfl)
{
  int t = blockIdx.x; int tid = threadIdx.x;
  __shared__ float red[256];
  float vloc[8];
  float ss = 0.f;
  #pragma unroll
  for (int i=0;i<8;i++){
    int cc = tid + i*256;
    float y = ypart[(size_t)t*DSSM + cc]
            + ypart[(size_t)(TOK   + t)*DSSM + cc]
            + ypart[(size_t)(2*TOK + t)*DSSM + cc]
            + ypart[(size_t)(3*TOK + t)*DSSM + cc]
            + ypart[(size_t)(4*TOK + t)*DSSM + cc];
    float z = zx[(size_t)t*DPROJP + cc];
    float v = y * (z / (1.f + expf(-z)));
    vloc[i] = v; ss += v*v;
  }
  red[tid] = ss; __syncthreads();
  #pragma unroll
  for (int s=128; s>0; s>>=1){ if (tid < s) red[tid] += red[tid+s]; __syncthreads(); }
  float rs = rsqrtf(red[0]*(1.f/2048.f) + 1e-5f);
  #pragma unroll
  for (int i=0;i<8;i++){
    int cc = tid + i*256;
    float vv = vloc[i]*rs*normw[cc];
    ushort hi = f2bf(vv);
    yfh[(size_t)t*DSSM + cc] = hi;
    yfl[(size_t)t*DSSM + cc] = f2bf(vv - bf2f(hi));
  }
}

extern "C" void kernel_launch(void* const* d_in, const int* in_sizes, int n_in,
                              void* d_out, int out_size, void* d_ws, size_t ws_size,
                              hipStream_t stream)
{
  const float* u      = (const float*)d_in[0];
  const float* W_in   = (const float*)d_in[1];
  const float* W_out  = (const float*)d_in[2];
  const float* dt_bias= (const float*)d_in[3];
  const float* A_log  = (const float*)d_in[4];
  const float* Dp     = (const float*)d_in[5];
  const float* B_bias = (const float*)d_in[6];
  const float* C_bias = (const float*)d_in[7];
  const float* Bnw    = (const float*)d_in[8];
  const float* Cnw    = (const float*)d_in[9];
  const float* normw  = (const float*)d_in[10];
  float* out = (float*)d_out;

  char* ws = (char*)d_ws;
  size_t o = 0;
  auto alloc = [&](size_t bytes)->char*{
    char* r = ws + o; o = (o + bytes + 255) & ~(size_t)255; return r;
  };
  ushort* WTh  = (ushort*)alloc((size_t)DPROJP*DMODEL*2);
  ushort* WTl  = (ushort*)alloc((size_t)DPROJP*DMODEL*2);
  ushort* WoTh = (ushort*)alloc((size_t)DMODEL*DSSM*2);
  ushort* WoTl = (ushort*)alloc((size_t)DMODEL*DSSM*2);
  ushort* uh   = (ushort*)alloc((size_t)TOK*DMODEL*2);
  ushort* ul   = (ushort*)alloc((size_t)TOK*DMODEL*2);
  ushort* yfh  = (ushort*)alloc((size_t)TOK*DSSM*2);
  ushort* yfl  = (ushort*)alloc((size_t)TOK*DSSM*2);
  float*  zx   = (float*)alloc((size_t)TOK*DPROJP*4);
  float*  cosm = (float*)alloc((size_t)TOK*64*4);
  float*  sinm = (float*)alloc((size_t)TOK*64*4);
  float*  Bgb  = (float*)alloc((size_t)TOK*128*4);
  float*  Cgb  = (float*)alloc((size_t)TOK*128*4);
  float4* scal = (float4*)alloc((size_t)TOK*32*16);
  float*  ypart= (float*)alloc((size_t)5*TOK*DSSM*4);
  float*  hcarry=(float*)alloc((size_t)2*32*NCH*64*128*4);
  float*  prefA =(float*)alloc((size_t)TOK*32*4);
  float*  Cpart =(float*)alloc((size_t)4*TOK*DMODEL*4);
  float*  xeb  = (float*)alloc((size_t)TOK*DSSM*4);
  float*  Beff = (float*)alloc((size_t)2*32*LSEQ*128*4);
  float*  pdt  = (float*)alloc((size_t)TOK*32*4);
  float*  padA = (float*)alloc((size_t)TOK*32*4);

  // weights -> transposed bf16 hi/lo
  transq_kernel<<<dim3(DPROJP/32, DMODEL/32), dim3(256), 0, stream>>>(W_in, WTh, WTl, DMODEL, DPROJ);
  transq_kernel<<<dim3(DMODEL/32, DSSM/32),   dim3(256), 0, stream>>>(W_out, WoTh, WoTl, DSSM, DMODEL);
  splitA_kernel<<<dim3(TOK*DMODEL/1024), dim3(256), 0, stream>>>(u, uh, ul);

  // in-proj
  gemmq_kernel<<<dim3(408), dim3(256), 0, stream>>>(uh, ul, WTh, WTl, zx, DMODEL, DMODEL, DPROJP, 51, 51);

  // cumsum + cos/sin
  cum2_kernel<<<dim3(128), dim3(512), 0, stream>>>(zx, cosm, sinm);

  // per-token elementwise
  ew_kernel<<<dim3(TOK), dim3(256), 0, stream>>>(zx, cosm, sinm, dt_bias, A_log,
                                                 B_bias, C_bias, Bnw, Cnw, Bgb, Cgb, scal);

  // scan input packing
  packx_kernel<<<dim3(512), dim3(256), 0, stream>>>(zx, scal, xeb);
  beff_kernel<<<dim3(TOK), dim3(128), 0, stream>>>(Bgb, scal, Beff);
  packs_kernel<<<dim3(2), dim3(256), 0, stream>>>(scal, pdt, padA, prefA);

  // chunked scan
  scan1_kernel<<<dim3(2048), dim3(256), 0, stream>>>(xeb, Beff, Cgb, pdt, padA, Dp, ypart, hcarry);
  scan2_kernel<<<dim3(2048), dim3(256), 0, stream>>>(hcarry, prefA);
  scan3_kernel<<<dim3(512),  dim3(256), 0, stream>>>(Cgb, hcarry, prefA, ypart);

  // gate + rms -> bf16 hi/lo
  fin_kernel<<<dim3(TOK), dim3(256), 0, stream>>>(zx, ypart, normw, yfh, yfl);

  // out-proj: split-K=4
  gemmq_kernel<<<dim3(256), dim3(256), 0, stream>>>(yfh, yfl, WoTh, WoTl, Cpart, DSSM, 512, DMODEL, 8, 32);
  red4_kernel<<<dim3(TOK*DMODEL/1024), dim3(256), 0, stream>>>(Cpart, out);
}

// Round 5
// 217.022 us; speedup vs baseline: 1.4027x; 1.4027x over previous
//
#include <hip/hip_runtime.h>
#include <hip/hip_bf16.h>
#include <cstdint>

#define TOK 1024      // B*L
#define LSEQ 512
#define DMODEL 1024
#define DPROJ 6464
#define DPROJP 6528   // padded to 51*128
#define DSSM 2048
#define NHEADS 32
#define HEADDIM 64
#define DSTATE 128
#define NCH 8
#define CL 64

typedef __attribute__((ext_vector_type(4))) float f32x4;
typedef __attribute__((ext_vector_type(8))) short s16x8;
typedef __attribute__((ext_vector_type(4))) ushort u16x4;

__device__ __forceinline__ ushort f2bf(float x){
  union { float f; uint32_t u; } v; v.f = x;
  uint32_t r = (v.u + 0x7FFFu + ((v.u >> 16) & 1u)) >> 16;
  return (ushort)r;
}
__device__ __forceinline__ float bf2f(ushort h){
  union { uint32_t u; float f; } v; v.u = ((uint32_t)h) << 16;
  return v.f;
}
__device__ __forceinline__ float silu_f(float x){
  return x*__builtin_amdgcn_rcpf(1.f+__expf(-x));
}

__device__ __forceinline__ void gload16(const ushort* g, ushort* l){
  __builtin_amdgcn_global_load_lds(
      (const __attribute__((address_space(1))) unsigned int*)g,
      (__attribute__((address_space(3))) unsigned int*)l, 16, 0, 0);
}

// build bf16 hi/lo A/B fragment (8 k-elements) from f32 LDS row
__device__ __forceinline__ void fragLD(const float* base, s16x8& h, s16x8& l){
  f32x4 a = *(const f32x4*)base;
  f32x4 b = *(const f32x4*)(base+4);
  #pragma unroll
  for (int j=0;j<4;j++){
    ushort hh = f2bf(a[j]); h[j]   = (short)hh; l[j]   = (short)f2bf(a[j]-bf2f(hh));
    hh = f2bf(b[j]);        h[4+j] = (short)hh; l[4+j] = (short)f2bf(b[j]-bf2f(hh));
  }
}
__device__ __forceinline__ f32x4 mfma3(const s16x8& ah, const s16x8& al,
                                       const s16x8& bh, const s16x8& bl, f32x4 acc){
  acc = __builtin_amdgcn_mfma_f32_16x16x32_bf16(ah, bh, acc, 0,0,0);
  acc = __builtin_amdgcn_mfma_f32_16x16x32_bf16(ah, bl, acc, 0,0,0);
  acc = __builtin_amdgcn_mfma_f32_16x16x32_bf16(al, bh, acc, 0,0,0);
  return acc;
}

// ------------- transpose W (K x N) -> bf16 hi/lo (Npad x K) -------------
__global__ __launch_bounds__(256) void transq_kernel(const float* __restrict__ W,
    ushort* __restrict__ Th, ushort* __restrict__ Tl, int K, int N)
{
  __shared__ float tile[32][33];
  int tx = threadIdx.x & 31, ty = threadIdx.x >> 5;
  int n = blockIdx.x*32 + tx;
  #pragma unroll
  for (int i=0;i<4;i++){
    int k = blockIdx.y*32 + ty + i*8;
    tile[ty+i*8][tx] = (n < N) ? W[(size_t)k*N + n] : 0.f;
  }
  __syncthreads();
  #pragma unroll
  for (int i=0;i<4;i++){
    int nn = blockIdx.x*32 + ty + i*8;
    int kk = blockIdx.y*32 + tx;
    float v = tile[tx][ty+i*8];
    ushort hi = f2bf(v);
    ushort lo = f2bf(v - bf2f(hi));
    Th[(size_t)nn*K + kk] = hi;
    Tl[(size_t)nn*K + kk] = lo;
  }
}

// ------------- split fp32 matrix -> bf16 hi/lo -------------
__global__ __launch_bounds__(256) void splitA_kernel(const float* __restrict__ A,
    ushort* __restrict__ H, ushort* __restrict__ Lo)
{
  int i = blockIdx.x*256 + threadIdx.x;
  f32x4 v = ((const f32x4*)A)[i];
  u16x4 h, l;
  #pragma unroll
  for (int j=0;j<4;j++){
    ushort hh = f2bf(v[j]);
    h[j] = hh; l[j] = f2bf(v[j] - bf2f(hh));
  }
  *(u16x4*)&H[(size_t)i*4]  = h;
  *(u16x4*)&Lo[(size_t)i*4] = l;
}

// ------------- GEMM (m97-style): 128x128 tile, global_load_lds staging -------------
__global__ __launch_bounds__(256) void gemmq_kernel(
    const ushort* __restrict__ Ah, const ushort* __restrict__ Al,
    const ushort* __restrict__ Bh, const ushort* __restrict__ Bl,
    float* __restrict__ C, int K, int kLen, int ldc, int nbn, int chunk)
{
  __shared__ ushort sAh[4096], sAl[4096], sBh[4096], sBl[4096];
  int bid = blockIdx.x;
  int newL = (bid & 7)*chunk + (bid >> 3);   // XCD-chunked swizzle
  int bm = newL & 7;
  int pan = newL >> 3;
  int bn = pan % nbn;
  int z  = pan / nbn;
  int k0 = z * kLen;
  C += (size_t)z * 1024 * ldc;

  int tid = threadIdx.x;
  int wid = tid >> 6, lane = tid & 63;
  int wr = wid >> 1, wc = wid & 1;
  int fr = lane & 15, kg = lane >> 4;
  f32x4 acc[4][4] = {};

  int srow = tid & 127, skg = tid >> 7;
  const ushort* gA_h = Ah + (size_t)(bm*128+srow)*K + k0 + skg*8;
  const ushort* gA_l = Al + (size_t)(bm*128+srow)*K + k0 + skg*8;
  const ushort* gB_h = Bh + (size_t)(bn*128+srow)*K + k0 + skg*8;
  const ushort* gB_l = Bl + (size_t)(bn*128+srow)*K + k0 + skg*8;
  ushort* dA_h = sAh + tid*8;
  ushort* dA_l = sAl + tid*8;
  ushort* dB_h = sBh + tid*8;
  ushort* dB_l = sBl + tid*8;

  int rA = kg*1024 + (wr*64 + fr)*8;
  int rB = kg*1024 + (wc*64 + fr)*8;
  int NK = kLen >> 5;

  gload16(gA_h, dA_h); gload16(gA_h+16, dA_h+2048);
  gload16(gA_l, dA_l); gload16(gA_l+16, dA_l+2048);
  gload16(gB_h, dB_h); gload16(gB_h+16, dB_h+2048);
  gload16(gB_l, dB_l); gload16(gB_l+16, dB_l+2048);

  for (int ks=0; ks<NK; ks++){
    __syncthreads();
    s16x8 afh[4], afl[4], bfh[4], bfl[4];
    #pragma unroll
    for (int i=0;i<4;i++){
      afh[i] = *(const s16x8*)&sAh[rA + i*128];
      afl[i] = *(const s16x8*)&sAl[rA + i*128];
      bfh[i] = *(const s16x8*)&sBh[rB + i*128];
      bfl[i] = *(const s16x8*)&sBl[rB + i*128];
    }
    __syncthreads();
    if (ks+1 < NK){
      int off = (ks+1)*32;
      gload16(gA_h+off, dA_h); gload16(gA_h+off+16, dA_h+2048);
      gload16(gA_l+off, dA_l); gload16(gA_l+off+16, dA_l+2048);
      gload16(gB_h+off, dB_h); gload16(gB_h+off+16, dB_h+2048);
      gload16(gB_l+off, dB_l); gload16(gB_l+off+16, dB_l+2048);
    }
    #pragma unroll
    for (int i=0;i<4;i++){
      #pragma unroll
      for (int j=0;j<4;j++){
        acc[i][j] = __builtin_amdgcn_mfma_f32_16x16x32_bf16(afh[i], bfh[j], acc[i][j], 0,0,0);
        acc[i][j] = __builtin_amdgcn_mfma_f32_16x16x32_bf16(afh[i], bfl[j], acc[i][j], 0,0,0);
        acc[i][j] = __builtin_amdgcn_mfma_f32_16x16x32_bf16(afl[i], bfh[j], acc[i][j], 0,0,0);
      }
    }
  }
  int rq = kg * 4;
  #pragma unroll
  for (int i=0;i<4;i++){
    #pragma unroll
    for (int j=0;j<4;j++){
      int row = bm*128 + wr*64 + i*16 + rq;
      int col = bn*128 + wc*64 + j*16 + fr;
      #pragma unroll
      for (int q=0;q<4;q++)
        C[(size_t)(row+q)*ldc + col] = acc[i][j][q];
    }
  }
}

// ------------- reduce 4 split-K partials -------------
__global__ __launch_bounds__(256) void red4_kernel(const float* __restrict__ P, float* __restrict__ O){
  int i = blockIdx.x*256 + threadIdx.x;
  f32x4 v = ((const f32x4*)P)[i];
  v += ((const f32x4*)P)[i + 262144];
  v += ((const f32x4*)P)[i + 2*262144];
  v += ((const f32x4*)P)[i + 3*262144];
  ((f32x4*)O)[i] = v;
}

// ------------- cumsum(theta) + mean-over-heads cos/sin -------------
__global__ __launch_bounds__(512) void cum2_kernel(const float* __restrict__ zx,
    float* __restrict__ cosm, float* __restrict__ sinm)
{
  __shared__ float wsum[8];
  int b = blockIdx.x >> 6, hd = blockIdx.x & 63;
  int l = threadIdx.x, lane = l & 63, w = l >> 6;
  float accc = 0.f, accs = 0.f;
  const float* base = zx + (size_t)(b*LSEQ)*DPROJP + 4416 + hd;
  for (int h = 0; h < 32; h++){
    float x = base[(size_t)l*DPROJP + h*64];
    #pragma unroll
    for (int m=1; m<64; m<<=1){
      float v = __shfl_up(x, m, 64);
      if (lane >= m) x += v;
    }
    if (lane == 63) wsum[w] = x;
    __syncthreads();
    float pre = 0.f;
    for (int i=0;i<w;i++) pre += wsum[i];
    x += pre;
    float s, c;
    __sincosf(x, &s, &c);
    accc += c; accs += s;
    __syncthreads();
  }
  int t = b*LSEQ + l;
  cosm[t*64+hd] = accc*(1.f/32.f);
  sinm[t*64+hd] = accs*(1.f/32.f);
}

// ------------- per-token: B/C rms+rope, dt/dA/lam/lamg pack -------------
__global__ __launch_bounds__(256) void ew_kernel(const float* __restrict__ zx,
    const float* __restrict__ cosm, const float* __restrict__ sinm,
    const float* __restrict__ dt_bias, const float* __restrict__ A_log,
    const float* __restrict__ B_bias, const float* __restrict__ C_bias,
    const float* __restrict__ Bnw, const float* __restrict__ Cnw,
    float* __restrict__ Bg, float* __restrict__ Cg, float4* __restrict__ scal)
{
  int t = blockIdx.x; int tid = threadIdx.x;
  __shared__ float red[256];
  __shared__ float nb[128], nc[128];
  const float* row = zx + (size_t)t*DPROJP;
  float v;
  if (tid < 128) v = row[4096 + tid] + B_bias[tid];
  else           v = row[4224 + (tid-128)] + C_bias[tid-128];
  red[tid] = v*v;
  __syncthreads();
  #pragma unroll
  for (int s=64; s>0; s>>=1){
    if ((tid & 127) < s) red[tid] += red[tid + s];
    __syncthreads();
  }
  float ms = red[(tid < 128) ? 0 : 128] * (1.f/128.f);
  float rs = rsqrtf(ms + 1e-5f);
  float w  = (tid < 128) ? Bnw[tid] : Cnw[tid-128];
  float nv = v * rs * w;
  if (tid < 128) nb[tid] = nv; else nc[tid-128] = nv;
  __syncthreads();
  if (tid < 64){
    float c = cosm[t*64+tid], s = sinm[t*64+tid];
    float a = nb[tid], bq = nb[tid+64];
    Bg[(size_t)t*128 + tid]      = a*c - bq*s;
    Bg[(size_t)t*128 + 64 + tid] = bq*c + a*s;
  } else if (tid < 128){
    int i = tid - 64;
    float c = cosm[t*64+i], s = sinm[t*64+i];
    float a = nc[i], bq = nc[i+64];
    Cg[(size_t)t*128 + i]      = a*c - bq*s;
    Cg[(size_t)t*128 + 64 + i] = bq*c + a*s;
  } else if (tid < 160){
    int hh = tid - 128;
    float dtr = row[4352 + hh] + dt_bias[hh];
    float dtv = (dtr > 20.f) ? dtr : log1pf(expf(dtr));
    float dA  = expf(-dtv * expf(A_log[hh]));
    float lr  = row[4384 + hh];
    float lam = 1.f/(1.f + expf(-lr));
    float lg = lam;
    #pragma unroll
    for (int m=1;m<32;m<<=1) lg += __shfl_xor(lg, m, 64);
    lg *= (1.f/32.f);
    scal[(size_t)t*32 + hh] = make_float4(dtv, dA, lam, lg);
  }
}

// ------------- pass 1: per-(b,h,chunk) attention-form local scan via MFMA -------------
__global__ __launch_bounds__(256, 1) void scanA_kernel(
    const float* __restrict__ zx, const float* __restrict__ Bg,
    const float* __restrict__ Cg, const float4* __restrict__ scal,
    const float* __restrict__ A_log, const float* __restrict__ Dp,
    float* __restrict__ ypart, float* __restrict__ hcarry,
    float* __restrict__ clog, float* __restrict__ AtotB)
{
  __shared__ __align__(16) float smC[64*132];   // C chunk [s][d]; later aliased by S' [t][s] pad 68
  __shared__ __align__(16) float smB[64*132];   // B_eff [s][d]
  __shared__ __align__(16) float smBT[128*68];  // B_eff^T * w[s]  [d][s]
  __shared__ __align__(16) float smX[64*68];    // xe^T [p][s]
  __shared__ __align__(16) float sDt[64], sLam[64], sLg[64], sCl[64], sW[64];
  float* sSp = smC;

  int blk = blockIdx.x;            // (b*32+h)*8 + c
  int c = blk & 7, h = (blk>>3)&31, b = blk>>8;
  int idx = blk;
  int t0 = b*LSEQ + c*CL;
  int tid = threadIdx.x;
  int w = tid >> 6, lane = tid & 63;
  int fr = lane & 15, kq = lane >> 4;

  // ---- phase 0: stage C (all) + wave0 scalar prep ----
  {
    int s = tid >> 2, dq4 = (tid & 3) * 32;
    const float* src = Cg + (size_t)(t0+s)*128 + dq4;
    float* dst = smC + s*132 + dq4;
    #pragma unroll
    for (int i=0;i<8;i++) *(f32x4*)(dst + i*4) = *(const f32x4*)(src + i*4);
  }
  if (tid < 64){
    float4 sc = scal[(size_t)(t0+tid)*32 + h];
    float a  = __expf(A_log[h]);
    float cl = -sc.x * a * 1.44269504088896f;   // log2(dA)
    #pragma unroll
    for (int m=1; m<64; m<<=1){
      float v = __shfl_up(cl, m, 64);
      if (lane >= m) cl += v;
    }
    float cl63 = __shfl(cl, 63, 64);
    sDt[tid] = sc.x; sLam[tid] = sc.z; sLg[tid] = sc.w;
    sCl[tid] = cl;
    sW[tid]  = exp2f(cl63 - cl) * sc.x;
    clog[(size_t)idx*64 + tid] = cl;
    if (tid == 63) AtotB[idx] = exp2f(cl63);
  }
  __syncthreads();

  // ---- phase 1: stage B_eff (+transposed*w) and xe ----
  {
    int s = tid >> 2, dq4 = (tid & 3) * 32;
    float lg = sLg[s], wgt = sW[s];
    bool zp = (s == 0 && c == 0);
    const float* bc_p = Bg + (size_t)(t0+s)*128 + dq4;
    const float* bp_p = Bg + (size_t)(t0+s-1)*128 + dq4;
    #pragma unroll
    for (int i=0;i<32;i+=4){
      f32x4 bc = *(const f32x4*)(bc_p + i);
      f32x4 bp = zp ? (f32x4){0,0,0,0} : *(const f32x4*)(bp_p + i);
      f32x4 be = bp + lg*(bc - bp);
      *(f32x4*)(smB + s*132 + dq4 + i) = be;
      smBT[(dq4+i+0)*68 + s] = be.x * wgt;
      smBT[(dq4+i+1)*68 + s] = be.y * wgt;
      smBT[(dq4+i+2)*68 + s] = be.z * wgt;
      smBT[(dq4+i+3)*68 + s] = be.w * wgt;
    }
  }
  {
    int p = tid & 63, sg = tid >> 6;
    int s0 = sg*16;
    const float* xbase = zx + 2048 + h*64 + p;
    float xp_ = 0.f;
    if (!(s0 == 0 && c == 0))
      xp_ = silu_f(xbase[(size_t)(t0+s0-1)*DPROJP]);
    #pragma unroll
    for (int i=0;i<16;i++){
      int s = s0 + i;
      float xs = silu_f(xbase[(size_t)(t0+s)*DPROJP]);
      smX[p*68 + s] = xp_ + sLam[s]*(xs - xp_);
      xp_ = xs;
    }
  }
  __syncthreads();

  // ---- phase 2: GEMM1  S = C @ Beff^T (K=128), 3-term hi/lo ----
  int tq = w >> 1, sq = w & 1;
  f32x4 acc1[2][2] = {};
  #pragma unroll
  for (int kt=0; kt<4; kt++){
    s16x8 ah[2], al[2], bh[2], bl[2];
    #pragma unroll
    for (int i=0;i<2;i++)
      fragLD(smC + (tq*32 + i*16 + fr)*132 + kt*32 + kq*8, ah[i], al[i]);
    #pragma unroll
    for (int j=0;j<2;j++)
      fragLD(smB + (sq*32 + j*16 + fr)*132 + kt*32 + kq*8, bh[j], bl[j]);
    #pragma unroll
    for (int i=0;i<2;i++)
      #pragma unroll
      for (int j=0;j<2;j++)
        acc1[i][j] = mfma3(ah[i], al[i], bh[j], bl[j], acc1[i][j]);
  }
  // mask: S'[t,s] = S * exp2(cl_t - cl_s) * dt_s for s<=t else 0
  #pragma unroll
  for (int i=0;i<2;i++){
    int tb = tq*32 + i*16 + kq*4;
    f32x4 clt = *(const f32x4*)&sCl[tb];
    #pragma unroll
    for (int j=0;j<2;j++){
      int scol = sq*32 + j*16 + fr;
      float cls = sCl[scol], dts = sDt[scol];
      #pragma unroll
      for (int q=0;q<4;q++){
        float m = (tb+q >= scol) ? exp2f(clt[q]-cls)*dts : 0.f;
        acc1[i][j][q] *= m;
      }
    }
  }
  __syncthreads();                // all GEMM1 LDS reads finished
  #pragma unroll
  for (int i=0;i<2;i++){
    int tb = tq*32 + i*16 + kq*4;
    #pragma unroll
    for (int j=0;j<2;j++){
      int scol = sq*32 + j*16 + fr;
      #pragma unroll
      for (int q=0;q<4;q++)
        sSp[(tb+q)*68 + scol] = acc1[i][j][q];
    }
  }
  __syncthreads();

  float Dh = Dp[h];
  // ---- phase 3: GEMM2  Y = S' @ Xe  (K=64) + D*xe, write slice0 ----
  {
    f32x4 acc2[2][2] = {};
    #pragma unroll
    for (int kt=0; kt<2; kt++){
      s16x8 ah[2], al[2], bh[2], bl[2];
      #pragma unroll
      for (int i=0;i<2;i++)
        fragLD(sSp + (tq*32 + i*16 + fr)*68 + kt*32 + kq*8, ah[i], al[i]);
      #pragma unroll
      for (int j=0;j<2;j++)
        fragLD(smX + (sq*32 + j*16 + fr)*68 + kt*32 + kq*8, bh[j], bl[j]);
      #pragma unroll
      for (int i=0;i<2;i++)
        #pragma unroll
        for (int j=0;j<2;j++)
          acc2[i][j] = mfma3(ah[i], al[i], bh[j], bl[j], acc2[i][j]);
    }
    #pragma unroll
    for (int i=0;i<2;i++){
      int tb = tq*32 + i*16 + kq*4;
      #pragma unroll
      for (int j=0;j<2;j++){
        int pc = sq*32 + j*16 + fr;
        #pragma unroll
        for (int q=0;q<4;q++){
          float y = acc2[i][j][q] + Dh * smX[pc*68 + tb + q];
          ypart[(size_t)(t0+tb+q)*DSSM + h*64 + pc] = y;
        }
      }
    }
  }

  // ---- phase 4: GEMM4  H_local = (w-scaled Xe)^T ... = Xe @ BT (K=64) ----
  {
    f32x4 acc4[2][4] = {};
    int ph = w >> 1, dh = w & 1;
    #pragma unroll
    for (int kt=0; kt<2; kt++){
      s16x8 ah[2], al[2], bh[4], bl[4];
      #pragma unroll
      for (int i=0;i<2;i++)
        fragLD(smX + (ph*32 + i*16 + fr)*68 + kt*32 + kq*8, ah[i], al[i]);
      #pragma unroll
      for (int j=0;j<4;j++)
        fragLD(smBT + (dh*64 + j*16 + fr)*68 + kt*32 + kq*8, bh[j], bl[j]);
      #pragma unroll
      for (int i=0;i<2;i++)
        #pragma unroll
        for (int j=0;j<4;j++)
          acc4[i][j] = mfma3(ah[i], al[i], bh[j], bl[j], acc4[i][j]);
    }
    size_t hb = (size_t)idx * 64 * 128;
    #pragma unroll
    for (int i=0;i<2;i++){
      int pb = ph*32 + i*16 + kq*4;
      #pragma unroll
      for (int j=0;j<4;j++){
        int dc = dh*64 + j*16 + fr;
        #pragma unroll
        for (int q=0;q<4;q++)
          hcarry[hb + (size_t)(pb+q)*128 + dc] = acc4[i][j][q];
      }
    }
  }
}

// ------------- pass 2: propagate carries across chunks -------------
__global__ __launch_bounds__(256) void scan2_kernel(float* __restrict__ hcarry,
    const float* __restrict__ AtotB)
{
  int idx = blockIdx.x*256 + threadIdx.x;
  int d = idx & 127, pp = (idx >> 7) & 63, h = (idx >> 13) & 31, b = idx >> 18;
  size_t base = ((size_t)(b*32+h)*512 + pp)*128 + d;
  float Hin = 0.f;
  #pragma unroll
  for (int c=0; c<NCH; c++){
    float Atot = AtotB[(b*32+h)*8 + c];
    float S = hcarry[base + (size_t)c*8192];
    hcarry[base + (size_t)c*8192] = Hin;
    Hin = Atot*Hin + S;
  }
}

// ------------- pass 3: Y2 = exp2(cl_t) * C @ Hin^T  (K=128), write slice1 -------------
__global__ __launch_bounds__(256) void scanB_kernel(
    const float* __restrict__ Cg, const float* __restrict__ hcarry,
    const float* __restrict__ clog, float* __restrict__ ypart)
{
  __shared__ __align__(16) float smC[64*132];
  __shared__ __align__(16) float smH[64*132];   // Hin [p][d]
  __shared__ __align__(16) float sK[64];
  int blk = blockIdx.x;
  int c = blk & 7, h = (blk>>3)&31, b = blk>>8;
  int idx = blk;
  int t0 = b*LSEQ + c*CL;
  int tid = threadIdx.x;
  int w = tid >> 6, lane = tid & 63;
  int fr = lane & 15, kq = lane >> 4;
  {
    int s = tid >> 2, dq4 = (tid & 3) * 32;
    const float* src = Cg + (size_t)(t0+s)*128 + dq4;
    float* dst = smC + s*132 + dq4;
    #pragma unroll
    for (int i=0;i<8;i++) *(f32x4*)(dst + i*4) = *(const f32x4*)(src + i*4);
    const float* hs = hcarry + (size_t)idx*8192 + (size_t)s*128 + dq4;
    float* hd = smH + s*132 + dq4;
    #pragma unroll
    for (int i=0;i<8;i++) *(f32x4*)(hd + i*4) = *(const f32x4*)(hs + i*4);
  }
  if (tid < 64) sK[tid] = exp2f(clog[(size_t)idx*64 + tid]);
  __syncthreads();

  int tq = w >> 1, pq = w & 1;
  f32x4 acc[2][2] = {};
  #pragma unroll
  for (int kt=0; kt<4; kt++){
    s16x8 ah[2], al[2], bh[2], bl[2];
    #pragma unroll
    for (int i=0;i<2;i++)
      fragLD(smC + (tq*32 + i*16 + fr)*132 + kt*32 + kq*8, ah[i], al[i]);
    #pragma unroll
    for (int j=0;j<2;j++)
      fragLD(smH + (pq*32 + j*16 + fr)*132 + kt*32 + kq*8, bh[j], bl[j]);
    #pragma unroll
    for (int i=0;i<2;i++)
      #pragma unroll
      for (int j=0;j<2;j++)
        acc[i][j] = mfma3(ah[i], al[i], bh[j], bl[j], acc[i][j]);
  }
  #pragma unroll
  for (int i=0;i<2;i++){
    int tb = tq*32 + i*16 + kq*4;
    f32x4 kv = *(const f32x4*)&sK[tb];
    #pragma unroll
    for (int j=0;j<2;j++){
      int pc = pq*32 + j*16 + fr;
      #pragma unroll
      for (int q=0;q<4;q++)
        ypart[(size_t)TOK*DSSM + (size_t)(t0+tb+q)*DSSM + h*64 + pc] = acc[i][j][q]*kv[q];
    }
  }
}

// ------------- final: sum 2 partials, *silu(z), rms*norm_w -> bf16 hi/lo -------------
__global__ __launch_bounds__(256) void fin_kernel(const float* __restrict__ zx,
    const float* __restrict__ ypart, const float* __restrict__ normw,
    ushort* __restrict__ yfh, ushort* __restrict__ yfl)
{
  int t = blockIdx.x; int tid = threadIdx.x;
  __shared__ float red[256];
  float vloc[8];
  float ss = 0.f;
  #pragma unroll
  for (int i=0;i<8;i++){
    int cc = tid + i*256;
    float y = ypart[(size_t)t*DSSM + cc]
            + ypart[(size_t)(TOK + t)*DSSM + cc];
    float z = zx[(size_t)t*DPROJP + cc];
    float v = y * (z / (1.f + expf(-z)));
    vloc[i] = v; ss += v*v;
  }
  red[tid] = ss; __syncthreads();
  #pragma unroll
  for (int s=128; s>0; s>>=1){ if (tid < s) red[tid] += red[tid+s]; __syncthreads(); }
  float rs = rsqrtf(red[0]*(1.f/2048.f) + 1e-5f);
  #pragma unroll
  for (int i=0;i<8;i++){
    int cc = tid + i*256;
    float vv = vloc[i]*rs*normw[cc];
    ushort hi = f2bf(vv);
    yfh[(size_t)t*DSSM + cc] = hi;
    yfl[(size_t)t*DSSM + cc] = f2bf(vv - bf2f(hi));
  }
}

extern "C" void kernel_launch(void* const* d_in, const int* in_sizes, int n_in,
                              void* d_out, int out_size, void* d_ws, size_t ws_size,
                              hipStream_t stream)
{
  const float* u      = (const float*)d_in[0];
  const float* W_in   = (const float*)d_in[1];
  const float* W_out  = (const float*)d_in[2];
  const float* dt_bias= (const float*)d_in[3];
  const float* A_log  = (const float*)d_in[4];
  const float* Dp     = (const float*)d_in[5];
  const float* B_bias = (const float*)d_in[6];
  const float* C_bias = (const float*)d_in[7];
  const float* Bnw    = (const float*)d_in[8];
  const float* Cnw    = (const float*)d_in[9];
  const float* normw  = (const float*)d_in[10];
  float* out = (float*)d_out;

  char* ws = (char*)d_ws;
  size_t o = 0;
  auto alloc = [&](size_t bytes)->char*{
    char* r = ws + o; o = (o + bytes + 255) & ~(size_t)255; return r;
  };
  ushort* WTh  = (ushort*)alloc((size_t)DPROJP*DMODEL*2);
  ushort* WTl  = (ushort*)alloc((size_t)DPROJP*DMODEL*2);
  ushort* WoTh = (ushort*)alloc((size_t)DMODEL*DSSM*2);
  ushort* WoTl = (ushort*)alloc((size_t)DMODEL*DSSM*2);
  ushort* uh   = (ushort*)alloc((size_t)TOK*DMODEL*2);
  ushort* ul   = (ushort*)alloc((size_t)TOK*DMODEL*2);
  ushort* yfh  = (ushort*)alloc((size_t)TOK*DSSM*2);
  ushort* yfl  = (ushort*)alloc((size_t)TOK*DSSM*2);
  float*  zx   = (float*)alloc((size_t)TOK*DPROJP*4);
  float*  cosm = (float*)alloc((size_t)TOK*64*4);
  float*  sinm = (float*)alloc((size_t)TOK*64*4);
  float*  Bgb  = (float*)alloc((size_t)TOK*128*4);
  float*  Cgb  = (float*)alloc((size_t)TOK*128*4);
  float4* scal = (float4*)alloc((size_t)TOK*32*16);
  float*  ypart= (float*)alloc((size_t)2*TOK*DSSM*4);
  float*  hcarry=(float*)alloc((size_t)2*32*NCH*64*128*4);
  float*  clog = (float*)alloc((size_t)512*64*4);
  float*  AtotB= (float*)alloc((size_t)512*4);
  float*  Cpart =(float*)alloc((size_t)4*TOK*DMODEL*4);

  // weights -> transposed bf16 hi/lo
  transq_kernel<<<dim3(DPROJP/32, DMODEL/32), dim3(256), 0, stream>>>(W_in, WTh, WTl, DMODEL, DPROJ);
  transq_kernel<<<dim3(DMODEL/32, DSSM/32),   dim3(256), 0, stream>>>(W_out, WoTh, WoTl, DSSM, DMODEL);
  splitA_kernel<<<dim3(TOK*DMODEL/1024), dim3(256), 0, stream>>>(u, uh, ul);

  // in-proj
  gemmq_kernel<<<dim3(408), dim3(256), 0, stream>>>(uh, ul, WTh, WTl, zx, DMODEL, DMODEL, DPROJP, 51, 51);

  // cumsum + cos/sin
  cum2_kernel<<<dim3(128), dim3(512), 0, stream>>>(zx, cosm, sinm);

  // per-token elementwise
  ew_kernel<<<dim3(TOK), dim3(256), 0, stream>>>(zx, cosm, sinm, dt_bias, A_log,
                                                 B_bias, C_bias, Bnw, Cnw, Bgb, Cgb, scal);

  // attention-form chunked scan
  scanA_kernel<<<dim3(512),  dim3(256), 0, stream>>>(zx, Bgb, Cgb, scal, A_log, Dp,
                                                     ypart, hcarry, clog, AtotB);
  scan2_kernel<<<dim3(2048), dim3(256), 0, stream>>>(hcarry, AtotB);
  scanB_kernel<<<dim3(512),  dim3(256), 0, stream>>>(Cgb, hcarry, clog, ypart);

  // gate + rms -> bf16 hi/lo
  fin_kernel<<<dim3(TOK), dim3(256), 0, stream>>>(zx, ypart, normw, yfh, yfl);

  // out-proj: split-K=4
  gemmq_kernel<<<dim3(256), dim3(256), 0, stream>>>(yfh, yfl, WoTh, WoTl, Cpart, DSSM, 512, DMODEL, 8, 32);
  red4_kernel<<<dim3(TOK*DMODEL/1024), dim3(256), 0, stream>>>(Cpart, out);
}

// Round 6
// 202.137 us; speedup vs baseline: 1.5060x; 1.0736x over previous
//
#include <hip/hip_runtime.h>
#include <hip/hip_bf16.h>
#include <cstdint>

#define TOK 1024      // B*L
#define LSEQ 512
#define DMODEL 1024
#define DPROJ 6464
#define DPROJP 6528   // padded to 51*128
#define DSSM 2048
#define NHEADS 32
#define HEADDIM 64
#define DSTATE 128
#define NCH 8
#define CL 64

typedef __attribute__((ext_vector_type(4))) float f32x4;
typedef __attribute__((ext_vector_type(8))) short s16x8;
typedef __attribute__((ext_vector_type(4))) ushort u16x4;

__device__ __forceinline__ ushort f2bf(float x){
  union { float f; uint32_t u; } v; v.f = x;
  uint32_t r = (v.u + 0x7FFFu + ((v.u >> 16) & 1u)) >> 16;
  return (ushort)r;
}
__device__ __forceinline__ float bf2f(ushort h){
  union { uint32_t u; float f; } v; v.u = ((uint32_t)h) << 16;
  return v.f;
}
__device__ __forceinline__ float silu_f(float x){
  return x*__builtin_amdgcn_rcpf(1.f+__expf(-x));
}

__device__ __forceinline__ void gload16(const ushort* g, ushort* l){
  __builtin_amdgcn_global_load_lds(
      (const __attribute__((address_space(1))) unsigned int*)g,
      (__attribute__((address_space(3))) unsigned int*)l, 16, 0, 0);
}

// build bf16 hi/lo A/B fragment (8 k-elements) from f32 LDS row
__device__ __forceinline__ void fragLD(const float* base, s16x8& h, s16x8& l){
  f32x4 a = *(const f32x4*)base;
  f32x4 b = *(const f32x4*)(base+4);
  #pragma unroll
  for (int j=0;j<4;j++){
    ushort hh = f2bf(a[j]); h[j]   = (short)hh; l[j]   = (short)f2bf(a[j]-bf2f(hh));
    hh = f2bf(b[j]);        h[4+j] = (short)hh; l[4+j] = (short)f2bf(b[j]-bf2f(hh));
  }
}
__device__ __forceinline__ f32x4 mfma3(const s16x8& ah, const s16x8& al,
                                       const s16x8& bh, const s16x8& bl, f32x4 acc){
  acc = __builtin_amdgcn_mfma_f32_16x16x32_bf16(ah, bh, acc, 0,0,0);
  acc = __builtin_amdgcn_mfma_f32_16x16x32_bf16(ah, bl, acc, 0,0,0);
  acc = __builtin_amdgcn_mfma_f32_16x16x32_bf16(al, bh, acc, 0,0,0);
  return acc;
}

// ------------- transpose W (K x N) -> bf16 hi/lo (Npad x K) -------------
__global__ __launch_bounds__(256) void transq_kernel(const float* __restrict__ W,
    ushort* __restrict__ Th, ushort* __restrict__ Tl, int K, int N)
{
  __shared__ float tile[32][33];
  int tx = threadIdx.x & 31, ty = threadIdx.x >> 5;
  int n = blockIdx.x*32 + tx;
  #pragma unroll
  for (int i=0;i<4;i++){
    int k = blockIdx.y*32 + ty + i*8;
    tile[ty+i*8][tx] = (n < N) ? W[(size_t)k*N + n] : 0.f;
  }
  __syncthreads();
  #pragma unroll
  for (int i=0;i<4;i++){
    int nn = blockIdx.x*32 + ty + i*8;
    int kk = blockIdx.y*32 + tx;
    float v = tile[tx][ty+i*8];
    ushort hi = f2bf(v);
    ushort lo = f2bf(v - bf2f(hi));
    Th[(size_t)nn*K + kk] = hi;
    Tl[(size_t)nn*K + kk] = lo;
  }
}

// ------------- split fp32 matrix -> bf16 hi/lo -------------
__global__ __launch_bounds__(256) void splitA_kernel(const float* __restrict__ A,
    ushort* __restrict__ H, ushort* __restrict__ Lo)
{
  int i = blockIdx.x*256 + threadIdx.x;
  f32x4 v = ((const f32x4*)A)[i];
  u16x4 h, l;
  #pragma unroll
  for (int j=0;j<4;j++){
    ushort hh = f2bf(v[j]);
    h[j] = hh; l[j] = f2bf(v[j] - bf2f(hh));
  }
  *(u16x4*)&H[(size_t)i*4]  = h;
  *(u16x4*)&Lo[(size_t)i*4] = l;
}

// ------------- GEMM: per-block precision (bn>=lo_from -> 3-term hi/lo, else bf16 1-term) -------------
__global__ __launch_bounds__(256) void gemmq_kernel(
    const ushort* __restrict__ Ah, const ushort* __restrict__ Al,
    const ushort* __restrict__ Bh, const ushort* __restrict__ Bl,
    float* __restrict__ C, int K, int kLen, int ldc, int nbn, int chunk, int lo_from)
{
  __shared__ ushort sAh[4096], sAl[4096], sBh[4096], sBl[4096];
  int bid = blockIdx.x;
  int newL = (bid & 7)*chunk + (bid >> 3);   // XCD-chunked swizzle
  int bm = newL & 7;
  int pan = newL >> 3;
  int bn = pan % nbn;
  int z  = pan / nbn;
  int k0 = z * kLen;
  C += (size_t)z * 1024 * ldc;
  bool full = (bn >= lo_from);

  int tid = threadIdx.x;
  int wid = tid >> 6, lane = tid & 63;
  int wr = wid >> 1, wc = wid & 1;
  int fr = lane & 15, kg = lane >> 4;
  f32x4 acc[4][4] = {};

  int srow = tid & 127, skg = tid >> 7;
  const ushort* gA_h = Ah + (size_t)(bm*128+srow)*K + k0 + skg*8;
  const ushort* gA_l = Al + (size_t)(bm*128+srow)*K + k0 + skg*8;
  const ushort* gB_h = Bh + (size_t)(bn*128+srow)*K + k0 + skg*8;
  const ushort* gB_l = Bl + (size_t)(bn*128+srow)*K + k0 + skg*8;
  ushort* dA_h = sAh + tid*8;
  ushort* dA_l = sAl + tid*8;
  ushort* dB_h = sBh + tid*8;
  ushort* dB_l = sBl + tid*8;

  int rA = kg*1024 + (wr*64 + fr)*8;
  int rB = kg*1024 + (wc*64 + fr)*8;
  int NK = kLen >> 5;

  gload16(gA_h, dA_h); gload16(gA_h+16, dA_h+2048);
  gload16(gB_h, dB_h); gload16(gB_h+16, dB_h+2048);
  if (full){
    gload16(gA_l, dA_l); gload16(gA_l+16, dA_l+2048);
    gload16(gB_l, dB_l); gload16(gB_l+16, dB_l+2048);
  }

  for (int ks=0; ks<NK; ks++){
    __syncthreads();
    s16x8 afh[4], afl[4], bfh[4], bfl[4];
    #pragma unroll
    for (int i=0;i<4;i++){
      afh[i] = *(const s16x8*)&sAh[rA + i*128];
      bfh[i] = *(const s16x8*)&sBh[rB + i*128];
    }
    if (full){
      #pragma unroll
      for (int i=0;i<4;i++){
        afl[i] = *(const s16x8*)&sAl[rA + i*128];
        bfl[i] = *(const s16x8*)&sBl[rB + i*128];
      }
    }
    __syncthreads();
    if (ks+1 < NK){
      int off = (ks+1)*32;
      gload16(gA_h+off, dA_h); gload16(gA_h+off+16, dA_h+2048);
      gload16(gB_h+off, dB_h); gload16(gB_h+off+16, dB_h+2048);
      if (full){
        gload16(gA_l+off, dA_l); gload16(gA_l+off+16, dA_l+2048);
        gload16(gB_l+off, dB_l); gload16(gB_l+off+16, dB_l+2048);
      }
    }
    #pragma unroll
    for (int i=0;i<4;i++)
      #pragma unroll
      for (int j=0;j<4;j++)
        acc[i][j] = __builtin_amdgcn_mfma_f32_16x16x32_bf16(afh[i], bfh[j], acc[i][j], 0,0,0);
    if (full){
      #pragma unroll
      for (int i=0;i<4;i++)
        #pragma unroll
        for (int j=0;j<4;j++){
          acc[i][j] = __builtin_amdgcn_mfma_f32_16x16x32_bf16(afh[i], bfl[j], acc[i][j], 0,0,0);
          acc[i][j] = __builtin_amdgcn_mfma_f32_16x16x32_bf16(afl[i], bfh[j], acc[i][j], 0,0,0);
        }
    }
  }
  int rq = kg * 4;
  #pragma unroll
  for (int i=0;i<4;i++){
    #pragma unroll
    for (int j=0;j<4;j++){
      int row = bm*128 + wr*64 + i*16 + rq;
      int col = bn*128 + wc*64 + j*16 + fr;
      #pragma unroll
      for (int q=0;q<4;q++)
        C[(size_t)(row+q)*ldc + col] = acc[i][j][q];
    }
  }
}

// ------------- reduce 4 split-K partials -------------
__global__ __launch_bounds__(256) void red4_kernel(const float* __restrict__ P, float* __restrict__ O){
  int i = blockIdx.x*256 + threadIdx.x;
  f32x4 v = ((const f32x4*)P)[i];
  v += ((const f32x4*)P)[i + 262144];
  v += ((const f32x4*)P)[i + 2*262144];
  v += ((const f32x4*)P)[i + 3*262144];
  ((f32x4*)O)[i] = v;
}

// ------------- transpose theta section: zx[t][4416+col] -> thT[b][col][l] -------------
__global__ __launch_bounds__(256) void thT_kernel(const float* __restrict__ zx,
    float* __restrict__ thT)
{
  __shared__ float tile[64][65];
  int ci = blockIdx.x, li = blockIdx.y, bb = blockIdx.z;
  int tx = threadIdx.x & 63, ty = threadIdx.x >> 6;
  const float* src = zx + (size_t)(bb*LSEQ + li*64)*DPROJP + 4416 + ci*64;
  #pragma unroll
  for (int i=0;i<16;i++){
    int r = ty + i*4;
    tile[r][tx] = src[(size_t)r*DPROJP + tx];
  }
  __syncthreads();
  float* dst = thT + ((size_t)bb*2048 + ci*64)*512 + (size_t)li*64;
  #pragma unroll
  for (int i=0;i<16;i++){
    int r = ty + i*4;
    dst[(size_t)r*512 + tx] = tile[tx][r];
  }
}

// ------------- cumsum(theta) + mean-over-heads cos/sin (coalesced via thT) -------------
__global__ __launch_bounds__(512) void cum2_kernel(const float* __restrict__ thT,
    float* __restrict__ cosm, float* __restrict__ sinm)
{
  __shared__ float wsum[8];
  int b = blockIdx.x >> 6, hd = blockIdx.x & 63;
  int l = threadIdx.x, lane = l & 63, w = l >> 6;
  float accc = 0.f, accs = 0.f;
  const float* base = thT + (size_t)b*2048*512 + (size_t)hd*512;
  for (int h = 0; h < 32; h++){
    float x = base[(size_t)h*64*512 + l];
    #pragma unroll
    for (int m=1; m<64; m<<=1){
      float v = __shfl_up(x, m, 64);
      if (lane >= m) x += v;
    }
    if (lane == 63) wsum[w] = x;
    __syncthreads();
    float pre = 0.f;
    for (int i=0;i<w;i++) pre += wsum[i];
    x += pre;
    float s, c;
    __sincosf(x, &s, &c);
    accc += c; accs += s;
    __syncthreads();
  }
  int t = b*LSEQ + l;
  cosm[t*64+hd] = accc*(1.f/32.f);
  sinm[t*64+hd] = accs*(1.f/32.f);
}

// ------------- per-token: B/C rms+rope, dt/dA/lam/lamg pack -------------
__global__ __launch_bounds__(256) void ew_kernel(const float* __restrict__ zx,
    const float* __restrict__ cosm, const float* __restrict__ sinm,
    const float* __restrict__ dt_bias, const float* __restrict__ A_log,
    const float* __restrict__ B_bias, const float* __restrict__ C_bias,
    const float* __restrict__ Bnw, const float* __restrict__ Cnw,
    float* __restrict__ Bg, float* __restrict__ Cg, float4* __restrict__ scal)
{
  int t = blockIdx.x; int tid = threadIdx.x;
  __shared__ float red[256];
  __shared__ float nb[128], nc[128];
  const float* row = zx + (size_t)t*DPROJP;
  float v;
  if (tid < 128) v = row[4096 + tid] + B_bias[tid];
  else           v = row[4224 + (tid-128)] + C_bias[tid-128];
  red[tid] = v*v;
  __syncthreads();
  #pragma unroll
  for (int s=64; s>0; s>>=1){
    if ((tid & 127) < s) red[tid] += red[tid + s];
    __syncthreads();
  }
  float ms = red[(tid < 128) ? 0 : 128] * (1.f/128.f);
  float rs = rsqrtf(ms + 1e-5f);
  float w  = (tid < 128) ? Bnw[tid] : Cnw[tid-128];
  float nv = v * rs * w;
  if (tid < 128) nb[tid] = nv; else nc[tid-128] = nv;
  __syncthreads();
  if (tid < 64){
    float c = cosm[t*64+tid], s = sinm[t*64+tid];
    float a = nb[tid], bq = nb[tid+64];
    Bg[(size_t)t*128 + tid]      = a*c - bq*s;
    Bg[(size_t)t*128 + 64 + tid] = bq*c + a*s;
  } else if (tid < 128){
    int i = tid - 64;
    float c = cosm[t*64+i], s = sinm[t*64+i];
    float a = nc[i], bq = nc[i+64];
    Cg[(size_t)t*128 + i]      = a*c - bq*s;
    Cg[(size_t)t*128 + 64 + i] = bq*c + a*s;
  } else if (tid < 160){
    int hh = tid - 128;
    float dtr = row[4352 + hh] + dt_bias[hh];
    float dtv = (dtr > 20.f) ? dtr : log1pf(expf(dtr));
    float dA  = expf(-dtv * expf(A_log[hh]));
    float lr  = row[4384 + hh];
    float lam = 1.f/(1.f + expf(-lr));
    float lg = lam;
    #pragma unroll
    for (int m=1;m<32;m<<=1) lg += __shfl_xor(lg, m, 64);
    lg *= (1.f/32.f);
    scal[(size_t)t*32 + hh] = make_float4(dtv, dA, lam, lg);
  }
}

// ------------- pass 1: per-(b,h,chunk) attention-form local scan via MFMA -------------
__global__ __launch_bounds__(256, 1) void scanA_kernel(
    const float* __restrict__ zx, const float* __restrict__ Bg,
    const float* __restrict__ Cg, const float4* __restrict__ scal,
    const float* __restrict__ A_log, const float* __restrict__ Dp,
    float* __restrict__ ypart, float* __restrict__ hcarry,
    float* __restrict__ clog, float* __restrict__ AtotB)
{
  __shared__ __align__(16) float smC[64*132];   // C chunk [s][d]; later aliased by S' [t][s] pad 68
  __shared__ __align__(16) float smB[64*132];   // B_eff [s][d]
  __shared__ __align__(16) float smBT[128*68];  // B_eff^T * w[s]  [d][s]
  __shared__ __align__(16) float smX[64*68];    // xe^T [p][s]
  __shared__ __align__(16) float sDt[64], sLam[64], sLg[64], sCl[64], sW[64];
  float* sSp = smC;

  int blk = blockIdx.x;            // (b*32+h)*8 + c
  int c = blk & 7, h = (blk>>3)&31, b = blk>>8;
  int idx = blk;
  int t0 = b*LSEQ + c*CL;
  int tid = threadIdx.x;
  int w = tid >> 6, lane = tid & 63;
  int fr = lane & 15, kq = lane >> 4;

  // ---- phase 0: stage C (all) + wave0 scalar prep ----
  {
    int s = tid >> 2, dq4 = (tid & 3) * 32;
    const float* src = Cg + (size_t)(t0+s)*128 + dq4;
    float* dst = smC + s*132 + dq4;
    #pragma unroll
    for (int i=0;i<8;i++) *(f32x4*)(dst + i*4) = *(const f32x4*)(src + i*4);
  }
  if (tid < 64){
    float4 sc = scal[(size_t)(t0+tid)*32 + h];
    float a  = __expf(A_log[h]);
    float cl = -sc.x * a * 1.44269504088896f;   // log2(dA)
    #pragma unroll
    for (int m=1; m<64; m<<=1){
      float v = __shfl_up(cl, m, 64);
      if (lane >= m) cl += v;
    }
    float cl63 = __shfl(cl, 63, 64);
    sDt[tid] = sc.x; sLam[tid] = sc.z; sLg[tid] = sc.w;
    sCl[tid] = cl;
    sW[tid]  = exp2f(cl63 - cl) * sc.x;
    clog[(size_t)idx*64 + tid] = cl;
    if (tid == 63) AtotB[idx] = exp2f(cl63);
  }
  __syncthreads();

  // ---- phase 1: stage B_eff (+transposed*w) and xe ----
  {
    int s = tid >> 2, dq4 = (tid & 3) * 32;
    float lg = sLg[s], wgt = sW[s];
    bool zp = (s == 0 && c == 0);
    const float* bc_p = Bg + (size_t)(t0+s)*128 + dq4;
    const float* bp_p = Bg + (size_t)(t0+s-1)*128 + dq4;
    #pragma unroll
    for (int i=0;i<32;i+=4){
      f32x4 bc = *(const f32x4*)(bc_p + i);
      f32x4 bp = zp ? (f32x4){0,0,0,0} : *(const f32x4*)(bp_p + i);
      f32x4 be = bp + lg*(bc - bp);
      *(f32x4*)(smB + s*132 + dq4 + i) = be;
      smBT[(dq4+i+0)*68 + s] = be.x * wgt;
      smBT[(dq4+i+1)*68 + s] = be.y * wgt;
      smBT[(dq4+i+2)*68 + s] = be.z * wgt;
      smBT[(dq4+i+3)*68 + s] = be.w * wgt;
    }
  }
  {
    int p = tid & 63, sg = tid >> 6;
    int s0 = sg*16;
    const float* xbase = zx + 2048 + h*64 + p;
    float xp_ = 0.f;
    if (!(s0 == 0 && c == 0))
      xp_ = silu_f(xbase[(size_t)(t0+s0-1)*DPROJP]);
    #pragma unroll
    for (int i=0;i<16;i++){
      int s = s0 + i;
      float xs = silu_f(xbase[(size_t)(t0+s)*DPROJP]);
      smX[p*68 + s] = xp_ + sLam[s]*(xs - xp_);
      xp_ = xs;
    }
  }
  __syncthreads();

  // ---- phase 2: GEMM1  S = C @ Beff^T (K=128), 3-term hi/lo ----
  int tq = w >> 1, sq = w & 1;
  f32x4 acc1[2][2] = {};
  #pragma unroll
  for (int kt=0; kt<4; kt++){
    s16x8 ah[2], al[2], bh[2], bl[2];
    #pragma unroll
    for (int i=0;i<2;i++)
      fragLD(smC + (tq*32 + i*16 + fr)*132 + kt*32 + kq*8, ah[i], al[i]);
    #pragma unroll
    for (int j=0;j<2;j++)
      fragLD(smB + (sq*32 + j*16 + fr)*132 + kt*32 + kq*8, bh[j], bl[j]);
    #pragma unroll
    for (int i=0;i<2;i++)
      #pragma unroll
      for (int j=0;j<2;j++)
        acc1[i][j] = mfma3(ah[i], al[i], bh[j], bl[j], acc1[i][j]);
  }
  // mask: S'[t,s] = S * exp2(cl_t - cl_s) * dt_s for s<=t else 0
  #pragma unroll
  for (int i=0;i<2;i++){
    int tb = tq*32 + i*16 + kq*4;
    f32x4 clt = *(const f32x4*)&sCl[tb];
    #pragma unroll
    for (int j=0;j<2;j++){
      int scol = sq*32 + j*16 + fr;
      float cls = sCl[scol], dts = sDt[scol];
      #pragma unroll
      for (int q=0;q<4;q++){
        float m = (tb+q >= scol) ? exp2f(clt[q]-cls)*dts : 0.f;
        acc1[i][j][q] *= m;
      }
    }
  }
  __syncthreads();                // all GEMM1 LDS reads finished
  #pragma unroll
  for (int i=0;i<2;i++){
    int tb = tq*32 + i*16 + kq*4;
    #pragma unroll
    for (int j=0;j<2;j++){
      int scol = sq*32 + j*16 + fr;
      #pragma unroll
      for (int q=0;q<4;q++)
        sSp[(tb+q)*68 + scol] = acc1[i][j][q];
    }
  }
  __syncthreads();

  float Dh = Dp[h];
  // ---- phase 3: GEMM2  Y = S' @ Xe  (K=64) + D*xe, write slice0 ----
  {
    f32x4 acc2[2][2] = {};
    #pragma unroll
    for (int kt=0; kt<2; kt++){
      s16x8 ah[2], al[2], bh[2], bl[2];
      #pragma unroll
      for (int i=0;i<2;i++)
        fragLD(sSp + (tq*32 + i*16 + fr)*68 + kt*32 + kq*8, ah[i], al[i]);
      #pragma unroll
      for (int j=0;j<2;j++)
        fragLD(smX + (sq*32 + j*16 + fr)*68 + kt*32 + kq*8, bh[j], bl[j]);
      #pragma unroll
      for (int i=0;i<2;i++)
        #pragma unroll
        for (int j=0;j<2;j++)
          acc2[i][j] = mfma3(ah[i], al[i], bh[j], bl[j], acc2[i][j]);
    }
    #pragma unroll
    for (int i=0;i<2;i++){
      int tb = tq*32 + i*16 + kq*4;
      #pragma unroll
      for (int j=0;j<2;j++){
        int pc = sq*32 + j*16 + fr;
        #pragma unroll
        for (int q=0;q<4;q++){
          float y = acc2[i][j][q] + Dh * smX[pc*68 + tb + q];
          ypart[(size_t)(t0+tb+q)*DSSM + h*64 + pc] = y;
        }
      }
    }
  }

  // ---- phase 4: GEMM4  H_local = Xe @ (w-scaled B)^T layout  (K=64) ----
  {
    f32x4 acc4[2][4] = {};
    int ph = w >> 1, dh = w & 1;
    #pragma unroll
    for (int kt=0; kt<2; kt++){
      s16x8 ah[2], al[2], bh[4], bl[4];
      #pragma unroll
      for (int i=0;i<2;i++)
        fragLD(smX + (ph*32 + i*16 + fr)*68 + kt*32 + kq*8, ah[i], al[i]);
      #pragma unroll
      for (int j=0;j<4;j++)
        fragLD(smBT + (dh*64 + j*16 + fr)*68 + kt*32 + kq*8, bh[j], bl[j]);
      #pragma unroll
      for (int i=0;i<2;i++)
        #pragma unroll
        for (int j=0;j<4;j++)
          acc4[i][j] = mfma3(ah[i], al[i], bh[j], bl[j], acc4[i][j]);
    }
    size_t hb = (size_t)idx * 64 * 128;
    #pragma unroll
    for (int i=0;i<2;i++){
      int pb = ph*32 + i*16 + kq*4;
      #pragma unroll
      for (int j=0;j<4;j++){
        int dc = dh*64 + j*16 + fr;
        #pragma unroll
        for (int q=0;q<4;q++)
          hcarry[hb + (size_t)(pb+q)*128 + dc] = acc4[i][j][q];
      }
    }
  }
}

// ------------- pass 2: propagate carries across chunks -------------
__global__ __launch_bounds__(256) void scan2_kernel(float* __restrict__ hcarry,
    const float* __restrict__ AtotB)
{
  int idx = blockIdx.x*256 + threadIdx.x;
  int d = idx & 127, pp = (idx >> 7) & 63, h = (idx >> 13) & 31, b = idx >> 18;
  size_t base = ((size_t)(b*32+h)*512 + pp)*128 + d;
  float Hin = 0.f;
  #pragma unroll
  for (int c=0; c<NCH; c++){
    float Atot = AtotB[(b*32+h)*8 + c];
    float S = hcarry[base + (size_t)c*8192];
    hcarry[base + (size_t)c*8192] = Hin;
    Hin = Atot*Hin + S;
  }
}

// ------------- pass 3: Y2 = exp2(cl_t) * C @ Hin^T  (K=128), write slice1 -------------
__global__ __launch_bounds__(256) void scanB_kernel(
    const float* __restrict__ Cg, const float* __restrict__ hcarry,
    const float* __restrict__ clog, float* __restrict__ ypart)
{
  __shared__ __align__(16) float smC[64*132];
  __shared__ __align__(16) float smH[64*132];   // Hin [p][d]
  __shared__ __align__(16) float sK[64];
  int blk = blockIdx.x;
  int c = blk & 7, h = (blk>>3)&31, b = blk>>8;
  int idx = blk;
  int t0 = b*LSEQ + c*CL;
  int tid = threadIdx.x;
  int w = tid >> 6, lane = tid & 63;
  int fr = lane & 15, kq = lane >> 4;
  {
    int s = tid >> 2, dq4 = (tid & 3) * 32;
    const float* src = Cg + (size_t)(t0+s)*128 + dq4;
    float* dst = smC + s*132 + dq4;
    #pragma unroll
    for (int i=0;i<8;i++) *(f32x4*)(dst + i*4) = *(const f32x4*)(src + i*4);
    const float* hs = hcarry + (size_t)idx*8192 + (size_t)s*128 + dq4;
    float* hd = smH + s*132 + dq4;
    #pragma unroll
    for (int i=0;i<8;i++) *(f32x4*)(hd + i*4) = *(const f32x4*)(hs + i*4);
  }
  if (tid < 64) sK[tid] = exp2f(clog[(size_t)idx*64 + tid]);
  __syncthreads();

  int tq = w >> 1, pq = w & 1;
  f32x4 acc[2][2] = {};
  #pragma unroll
  for (int kt=0; kt<4; kt++){
    s16x8 ah[2], al[2], bh[2], bl[2];
    #pragma unroll
    for (int i=0;i<2;i++)
      fragLD(smC + (tq*32 + i*16 + fr)*132 + kt*32 + kq*8, ah[i], al[i]);
    #pragma unroll
    for (int j=0;j<2;j++)
      fragLD(smH + (pq*32 + j*16 + fr)*132 + kt*32 + kq*8, bh[j], bl[j]);
    #pragma unroll
    for (int i=0;i<2;i++)
      #pragma unroll
      for (int j=0;j<2;j++)
        acc[i][j] = mfma3(ah[i], al[i], bh[j], bl[j], acc[i][j]);
  }
  #pragma unroll
  for (int i=0;i<2;i++){
    int tb = tq*32 + i*16 + kq*4;
    f32x4 kv = *(const f32x4*)&sK[tb];
    #pragma unroll
    for (int j=0;j<2;j++){
      int pc = pq*32 + j*16 + fr;
      #pragma unroll
      for (int q=0;q<4;q++)
        ypart[(size_t)TOK*DSSM + (size_t)(t0+tb+q)*DSSM + h*64 + pc] = acc[i][j][q]*kv[q];
    }
  }
}

// ------------- final: sum 2 partials, *silu(z), rms*norm_w -> bf16 (hi only) -------------
__global__ __launch_bounds__(256) void fin_kernel(const float* __restrict__ zx,
    const float* __restrict__ ypart, const float* __restrict__ normw,
    ushort* __restrict__ yfh)
{
  int t = blockIdx.x; int tid = threadIdx.x;
  __shared__ float red[256];
  float vloc[8];
  float ss = 0.f;
  #pragma unroll
  for (int i=0;i<8;i++){
    int cc = tid + i*256;
    float y = ypart[(size_t)t*DSSM + cc]
            + ypart[(size_t)(TOK + t)*DSSM + cc];
    float z = zx[(size_t)t*DPROJP + cc];
    float v = y * (z / (1.f + expf(-z)));
    vloc[i] = v; ss += v*v;
  }
  red[tid] = ss; __syncthreads();
  #pragma unroll
  for (int s=128; s>0; s>>=1){ if (tid < s) red[tid] += red[tid+s]; __syncthreads(); }
  float rs = rsqrtf(red[0]*(1.f/2048.f) + 1e-5f);
  #pragma unroll
  for (int i=0;i<8;i++){
    int cc = tid + i*256;
    float vv = vloc[i]*rs*normw[cc];
    yfh[(size_t)t*DSSM + cc] = f2bf(vv);
  }
}

extern "C" void kernel_launch(void* const* d_in, const int* in_sizes, int n_in,
                              void* d_out, int out_size, void* d_ws, size_t ws_size,
                              hipStream_t stream)
{
  const float* u      = (const float*)d_in[0];
  const float* W_in   = (const float*)d_in[1];
  const float* W_out  = (const float*)d_in[2];
  const float* dt_bias= (const float*)d_in[3];
  const float* A_log  = (const float*)d_in[4];
  const float* Dp     = (const float*)d_in[5];
  const float* B_bias = (const float*)d_in[6];
  const float* C_bias = (const float*)d_in[7];
  const float* Bnw    = (const float*)d_in[8];
  const float* Cnw    = (const float*)d_in[9];
  const float* normw  = (const float*)d_in[10];
  float* out = (float*)d_out;

  char* ws = (char*)d_ws;
  size_t o = 0;
  auto alloc = [&](size_t bytes)->char*{
    char* r = ws + o; o = (o + bytes + 255) & ~(size_t)255; return r;
  };
  ushort* WTh  = (ushort*)alloc((size_t)DPROJP*DMODEL*2);
  ushort* WTl  = (ushort*)alloc((size_t)DPROJP*DMODEL*2);
  ushort* WoTh = (ushort*)alloc((size_t)DMODEL*DSSM*2);
  ushort* WoTl = (ushort*)alloc((size_t)DMODEL*DSSM*2);
  ushort* uh   = (ushort*)alloc((size_t)TOK*DMODEL*2);
  ushort* ul   = (ushort*)alloc((size_t)TOK*DMODEL*2);
  ushort* yfh  = (ushort*)alloc((size_t)TOK*DSSM*2);
  float*  zx   = (float*)alloc((size_t)TOK*DPROJP*4);
  float*  thT  = (float*)alloc((size_t)2*2048*512*4);
  float*  cosm = (float*)alloc((size_t)TOK*64*4);
  float*  sinm = (float*)alloc((size_t)TOK*64*4);
  float*  Bgb  = (float*)alloc((size_t)TOK*128*4);
  float*  Cgb  = (float*)alloc((size_t)TOK*128*4);
  float4* scal = (float4*)alloc((size_t)TOK*32*16);
  float*  ypart= (float*)alloc((size_t)2*TOK*DSSM*4);
  float*  hcarry=(float*)alloc((size_t)2*32*NCH*64*128*4);
  float*  clog = (float*)alloc((size_t)512*64*4);
  float*  AtotB= (float*)alloc((size_t)512*4);
  float*  Cpart =(float*)alloc((size_t)4*TOK*DMODEL*4);

  // weights -> transposed bf16 hi/lo
  transq_kernel<<<dim3(DPROJP/32, DMODEL/32), dim3(256), 0, stream>>>(W_in, WTh, WTl, DMODEL, DPROJ);
  transq_kernel<<<dim3(DMODEL/32, DSSM/32),   dim3(256), 0, stream>>>(W_out, WoTh, WoTl, DSSM, DMODEL);
  splitA_kernel<<<dim3(TOK*DMODEL/1024), dim3(256), 0, stream>>>(u, uh, ul);

  // in-proj: blocks with bn<32 (z,x) bf16 1-term; bn>=32 (B,C,dt,lam,theta) 3-term
  gemmq_kernel<<<dim3(408), dim3(256), 0, stream>>>(uh, ul, WTh, WTl, zx, DMODEL, DMODEL, DPROJP, 51, 51, 32);

  // theta transpose + cumsum + cos/sin
  thT_kernel<<<dim3(32, 8, 2), dim3(256), 0, stream>>>(zx, thT);
  cum2_kernel<<<dim3(128), dim3(512), 0, stream>>>(thT, cosm, sinm);

  // per-token elementwise
  ew_kernel<<<dim3(TOK), dim3(256), 0, stream>>>(zx, cosm, sinm, dt_bias, A_log,
                                                 B_bias, C_bias, Bnw, Cnw, Bgb, Cgb, scal);

  // attention-form chunked scan
  scanA_kernel<<<dim3(512),  dim3(256), 0, stream>>>(zx, Bgb, Cgb, scal, A_log, Dp,
                                                     ypart, hcarry, clog, AtotB);
  scan2_kernel<<<dim3(2048), dim3(256), 0, stream>>>(hcarry, AtotB);
  scanB_kernel<<<dim3(512),  dim3(256), 0, stream>>>(Cgb, hcarry, clog, ypart);

  // gate + rms -> bf16
  fin_kernel<<<dim3(TOK), dim3(256), 0, stream>>>(zx, ypart, normw, yfh);

  // out-proj: split-K=4, all 1-term bf16
  gemmq_kernel<<<dim3(256), dim3(256), 0, stream>>>(yfh, yfh, WoTh, WoTl, Cpart, DSSM, 512, DMODEL, 8, 32, 8);
  red4_kernel<<<dim3(TOK*DMODEL/1024), dim3(256), 0, stream>>>(Cpart, out);
}

// Round 7
// 143.708 us; speedup vs baseline: 2.1183x; 1.4066x over previous
//
#include <hip/hip_runtime.h>
#include <hip/hip_bf16.h>
#include <cstdint>

#define TOK 1024      // B*L
#define LSEQ 512
#define DMODEL 1024
#define DPROJ 6464
#define DPROJP 6528   // padded to 51*128
#define DSSM 2048
#define NHEADS 32
#define HEADDIM 64
#define DSTATE 128
#define NCH 8
#define CL 64

typedef __attribute__((ext_vector_type(4))) float f32x4;
typedef _Float16 f16;
typedef __attribute__((ext_vector_type(8))) _Float16 f16x8;
typedef __attribute__((ext_vector_type(4))) _Float16 f16x4;

__device__ __forceinline__ float silu_f(float x){
  return x*__builtin_amdgcn_rcpf(1.f+__expf(-x));
}

__device__ __forceinline__ void gload16(const void* g, void* l){
  __builtin_amdgcn_global_load_lds(
      (const __attribute__((address_space(1))) unsigned int*)g,
      (__attribute__((address_space(3))) unsigned int*)l, 16, 0, 0);
}

// f16 fragment (8 k-elements) from f32 LDS row
__device__ __forceinline__ f16x8 fragH(const float* base){
  f32x4 a = *(const f32x4*)base;
  f32x4 b = *(const f32x4*)(base+4);
  f16x8 h;
  #pragma unroll
  for (int j=0;j<4;j++){ h[j] = (f16)a[j]; h[4+j] = (f16)b[j]; }
  return h;
}

// ------------- transpose W (K x N) -> f16 (Npad x K) -------------
__global__ __launch_bounds__(256) void transqh_kernel(const float* __restrict__ W,
    f16* __restrict__ T, int K, int N)
{
  __shared__ float tile[32][33];
  int tx = threadIdx.x & 31, ty = threadIdx.x >> 5;
  int n = blockIdx.x*32 + tx;
  #pragma unroll
  for (int i=0;i<4;i++){
    int k = blockIdx.y*32 + ty + i*8;
    tile[ty+i*8][tx] = (n < N) ? W[(size_t)k*N + n] : 0.f;
  }
  __syncthreads();
  #pragma unroll
  for (int i=0;i<4;i++){
    int nn = blockIdx.x*32 + ty + i*8;
    int kk = blockIdx.y*32 + tx;
    T[(size_t)nn*K + kk] = (f16)tile[tx][ty+i*8];
  }
}

// ------------- fp32 -> f16 convert -------------
__global__ __launch_bounds__(256) void cvtH_kernel(const float* __restrict__ A,
    f16* __restrict__ H)
{
  int i = blockIdx.x*256 + threadIdx.x;
  f32x4 v = ((const f32x4*)A)[i];
  f16x4 h;
  #pragma unroll
  for (int j=0;j<4;j++) h[j] = (f16)v[j];
  *(f16x4*)&H[(size_t)i*4] = h;
}

// ------------- GEMM f16: C(MxN f32) = A(f16 MxK) * B^T(f16 NxK), BK=64 -------------
__global__ __launch_bounds__(256) void gemmh_kernel(
    const f16* __restrict__ A, const f16* __restrict__ B,
    float* __restrict__ C, int K, int kLen, int ldc, int nbn, int chunk)
{
  __shared__ ushort sA[8192], sB[8192];   // [8 kg][128 row][8 k] halfs, 16KB each
  int bid = blockIdx.x;
  int newL = (bid & 7)*chunk + (bid >> 3);   // XCD-chunked swizzle (grid = 8*chunk)
  int bm = newL & 7;
  int pan = newL >> 3;
  int bn = pan % nbn;
  int z  = pan / nbn;
  int k0 = z * kLen;
  C += (size_t)z * 1024 * ldc;

  int tid = threadIdx.x;
  int wid = tid >> 6, lane = tid & 63;
  int wr = wid >> 1, wc = wid & 1;
  int fr = lane & 15, kq = lane >> 4;
  f32x4 acc[4][4] = {};

  int srow = tid & 127, skg = tid >> 7;   // skg in {0,1}
  const f16* gA = A + (size_t)(bm*128+srow)*K + k0 + skg*8;
  const f16* gB = B + (size_t)(bn*128+srow)*K + k0 + skg*8;
  ushort* dA = sA + tid*8;
  ushort* dB = sB + tid*8;

  int rA = kq*1024 + (wr*64 + fr)*8;
  int rB = kq*1024 + (wc*64 + fr)*8;
  int NK = kLen >> 6;

  #pragma unroll
  for (int i=0;i<4;i++){
    gload16(gA + i*16, dA + i*2048);
    gload16(gB + i*16, dB + i*2048);
  }

  for (int ks=0; ks<NK; ks++){
    __syncthreads();
    f16x8 af0[4], bf0[4], af1[4], bf1[4];
    #pragma unroll
    for (int i=0;i<4;i++){
      af0[i] = *(const f16x8*)&sA[rA + i*128];
      bf0[i] = *(const f16x8*)&sB[rB + i*128];
      af1[i] = *(const f16x8*)&sA[rA + 4096 + i*128];
      bf1[i] = *(const f16x8*)&sB[rB + 4096 + i*128];
    }
    __syncthreads();
    if (ks+1 < NK){
      int off = (ks+1)*64;
      #pragma unroll
      for (int i=0;i<4;i++){
        gload16(gA + off + i*16, dA + i*2048);
        gload16(gB + off + i*16, dB + i*2048);
      }
    }
    #pragma unroll
    for (int i=0;i<4;i++)
      #pragma unroll
      for (int j=0;j<4;j++)
        acc[i][j] = __builtin_amdgcn_mfma_f32_16x16x32_f16(af0[i], bf0[j], acc[i][j], 0,0,0);
    #pragma unroll
    for (int i=0;i<4;i++)
      #pragma unroll
      for (int j=0;j<4;j++)
        acc[i][j] = __builtin_amdgcn_mfma_f32_16x16x32_f16(af1[i], bf1[j], acc[i][j], 0,0,0);
  }
  int rq = kq * 4;
  #pragma unroll
  for (int i=0;i<4;i++){
    #pragma unroll
    for (int j=0;j<4;j++){
      int row = bm*128 + wr*64 + i*16 + rq;
      int col = bn*128 + wc*64 + j*16 + fr;
      #pragma unroll
      for (int q=0;q<4;q++)
        C[(size_t)(row+q)*ldc + col] = acc[i][j][q];
    }
  }
}

// ------------- reduce 4 split-K partials -------------
__global__ __launch_bounds__(256) void red4_kernel(const float* __restrict__ P, float* __restrict__ O){
  int i = blockIdx.x*256 + threadIdx.x;
  f32x4 v = ((const f32x4*)P)[i];
  v += ((const f32x4*)P)[i + 262144];
  v += ((const f32x4*)P)[i + 2*262144];
  v += ((const f32x4*)P)[i + 3*262144];
  ((f32x4*)O)[i] = v;
}

// ------------- transpose theta section: zx[t][4416+col] -> thT[b][col][l] -------------
__global__ __launch_bounds__(256) void thT_kernel(const float* __restrict__ zx,
    float* __restrict__ thT)
{
  __shared__ float tile[64][65];
  int ci = blockIdx.x, li = blockIdx.y, bb = blockIdx.z;
  int tx = threadIdx.x & 63, ty = threadIdx.x >> 6;
  const float* src = zx + (size_t)(bb*LSEQ + li*64)*DPROJP + 4416 + ci*64;
  #pragma unroll
  for (int i=0;i<16;i++){
    int r = ty + i*4;
    tile[r][tx] = src[(size_t)r*DPROJP + tx];
  }
  __syncthreads();
  float* dst = thT + ((size_t)bb*2048 + ci*64)*512 + (size_t)li*64;
  #pragma unroll
  for (int i=0;i<16;i++){
    int r = ty + i*4;
    dst[(size_t)r*512 + tx] = tile[tx][r];
  }
}

// ------------- cumsum(theta) + cos/sin partial means (16 heads per block) -------------
__global__ __launch_bounds__(512) void cum2_kernel(const float* __restrict__ thT,
    float* __restrict__ cosm, float* __restrict__ sinm)
{
  __shared__ float wsum[8];
  int blk = blockIdx.x;            // 256 = b(2) x hd(64) x half(2)
  int half = blk & 1, hd = (blk >> 1) & 63, b = blk >> 7;
  int l = threadIdx.x, lane = l & 63, w = l >> 6;
  float accc = 0.f, accs = 0.f;
  const float* base = thT + (size_t)b*2048*512 + (size_t)(half*16)*64*512 + (size_t)hd*512;
  for (int h = 0; h < 16; h++){
    float x = base[(size_t)h*64*512 + l];
    #pragma unroll
    for (int m=1; m<64; m<<=1){
      float v = __shfl_up(x, m, 64);
      if (lane >= m) x += v;
    }
    if (lane == 63) wsum[w] = x;
    __syncthreads();
    float pre = 0.f;
    for (int i=0;i<w;i++) pre += wsum[i];
    x += pre;
    float s, c;
    __sincosf(x, &s, &c);
    accc += c; accs += s;
    __syncthreads();
  }
  int t = b*LSEQ + l;
  cosm[half*TOK*64 + t*64+hd] = accc*(1.f/32.f);
  sinm[half*TOK*64 + t*64+hd] = accs*(1.f/32.f);
}

// ------------- per-token: B/C rms+rope, dt/dA/lam/lamg pack -------------
__global__ __launch_bounds__(256) void ew_kernel(const float* __restrict__ zx,
    const float* __restrict__ cosm, const float* __restrict__ sinm,
    const float* __restrict__ dt_bias, const float* __restrict__ A_log,
    const float* __restrict__ B_bias, const float* __restrict__ C_bias,
    const float* __restrict__ Bnw, const float* __restrict__ Cnw,
    float* __restrict__ Bg, float* __restrict__ Cg, float4* __restrict__ scal)
{
  int t = blockIdx.x; int tid = threadIdx.x;
  __shared__ float red[256];
  __shared__ float nb[128], nc[128];
  const float* row = zx + (size_t)t*DPROJP;
  float v;
  if (tid < 128) v = row[4096 + tid] + B_bias[tid];
  else           v = row[4224 + (tid-128)] + C_bias[tid-128];
  red[tid] = v*v;
  __syncthreads();
  #pragma unroll
  for (int s=64; s>0; s>>=1){
    if ((tid & 127) < s) red[tid] += red[tid + s];
    __syncthreads();
  }
  float ms = red[(tid < 128) ? 0 : 128] * (1.f/128.f);
  float rs = rsqrtf(ms + 1e-5f);
  float w  = (tid < 128) ? Bnw[tid] : Cnw[tid-128];
  float nv = v * rs * w;
  if (tid < 128) nb[tid] = nv; else nc[tid-128] = nv;
  __syncthreads();
  if (tid < 64){
    float c = cosm[t*64+tid] + cosm[TOK*64 + t*64+tid];
    float s = sinm[t*64+tid] + sinm[TOK*64 + t*64+tid];
    float a = nb[tid], bq = nb[tid+64];
    Bg[(size_t)t*128 + tid]      = a*c - bq*s;
    Bg[(size_t)t*128 + 64 + tid] = bq*c + a*s;
  } else if (tid < 128){
    int i = tid - 64;
    float c = cosm[t*64+i] + cosm[TOK*64 + t*64+i];
    float s = sinm[t*64+i] + sinm[TOK*64 + t*64+i];
    float a = nc[i], bq = nc[i+64];
    Cg[(size_t)t*128 + i]      = a*c - bq*s;
    Cg[(size_t)t*128 + 64 + i] = bq*c + a*s;
  } else if (tid < 160){
    int hh = tid - 128;
    float dtr = row[4352 + hh] + dt_bias[hh];
    float dtv = (dtr > 20.f) ? dtr : log1pf(expf(dtr));
    float dA  = expf(-dtv * expf(A_log[hh]));
    float lr  = row[4384 + hh];
    float lam = 1.f/(1.f + expf(-lr));
    float lg = lam;
    #pragma unroll
    for (int m=1;m<32;m<<=1) lg += __shfl_xor(lg, m, 64);
    lg *= (1.f/32.f);
    scal[(size_t)t*32 + hh] = make_float4(dtv, dA, lam, lg);
  }
}

// ------------- pass 1: per-(b,h,chunk) attention-form local scan via MFMA (f16 frags) -------------
__global__ __launch_bounds__(256, 1) void scanA_kernel(
    const float* __restrict__ zx, const float* __restrict__ Bg,
    const float* __restrict__ Cg, const float4* __restrict__ scal,
    const float* __restrict__ A_log, const float* __restrict__ Dp,
    float* __restrict__ ypart, float* __restrict__ hcarry,
    float* __restrict__ clog, float* __restrict__ AtotB)
{
  __shared__ __align__(16) float smC[64*132];   // C chunk [s][d]; later aliased by S' [t][s] pad 68
  __shared__ __align__(16) float smB[64*132];   // B_eff [s][d]
  __shared__ __align__(16) float smBT[128*68];  // B_eff^T * w[s]  [d][s]
  __shared__ __align__(16) float smX[64*68];    // xe^T [p][s]
  __shared__ __align__(16) float sDt[64], sLam[64], sLg[64], sCl[64], sW[64];
  float* sSp = smC;

  int blk = blockIdx.x;            // (b*32+h)*8 + c
  int c = blk & 7, h = (blk>>3)&31, b = blk>>8;
  int idx = blk;
  int t0 = b*LSEQ + c*CL;
  int tid = threadIdx.x;
  int w = tid >> 6, lane = tid & 63;
  int fr = lane & 15, kq = lane >> 4;

  // ---- phase 0: stage C (all) + wave0 scalar prep ----
  {
    int s = tid >> 2, dq4 = (tid & 3) * 32;
    const float* src = Cg + (size_t)(t0+s)*128 + dq4;
    float* dst = smC + s*132 + dq4;
    #pragma unroll
    for (int i=0;i<8;i++) *(f32x4*)(dst + i*4) = *(const f32x4*)(src + i*4);
  }
  if (tid < 64){
    float4 sc = scal[(size_t)(t0+tid)*32 + h];
    float a  = __expf(A_log[h]);
    float cl = -sc.x * a * 1.44269504088896f;   // log2(dA)
    #pragma unroll
    for (int m=1; m<64; m<<=1){
      float v = __shfl_up(cl, m, 64);
      if (lane >= m) cl += v;
    }
    float cl63 = __shfl(cl, 63, 64);
    sDt[tid] = sc.x; sLam[tid] = sc.z; sLg[tid] = sc.w;
    sCl[tid] = cl;
    sW[tid]  = exp2f(cl63 - cl) * sc.x;
    clog[(size_t)idx*64 + tid] = cl;
    if (tid == 63) AtotB[idx] = exp2f(cl63);
  }
  __syncthreads();

  // ---- phase 1: stage B_eff (+transposed*w) and xe ----
  {
    int s = tid >> 2, dq4 = (tid & 3) * 32;
    float lg = sLg[s], wgt = sW[s];
    bool zp = (s == 0 && c == 0);
    const float* bc_p = Bg + (size_t)(t0+s)*128 + dq4;
    const float* bp_p = Bg + (size_t)(t0+s-1)*128 + dq4;
    #pragma unroll
    for (int i=0;i<32;i+=4){
      f32x4 bc = *(const f32x4*)(bc_p + i);
      f32x4 bp = zp ? (f32x4){0,0,0,0} : *(const f32x4*)(bp_p + i);
      f32x4 be = bp + lg*(bc - bp);
      *(f32x4*)(smB + s*132 + dq4 + i) = be;
      smBT[(dq4+i+0)*68 + s] = be.x * wgt;
      smBT[(dq4+i+1)*68 + s] = be.y * wgt;
      smBT[(dq4+i+2)*68 + s] = be.z * wgt;
      smBT[(dq4+i+3)*68 + s] = be.w * wgt;
    }
  }
  {
    int p = tid & 63, sg = tid >> 6;
    int s0 = sg*16;
    const float* xbase = zx + 2048 + h*64 + p;
    float xp_ = 0.f;
    if (!(s0 == 0 && c == 0))
      xp_ = silu_f(xbase[(size_t)(t0+s0-1)*DPROJP]);
    #pragma unroll
    for (int i=0;i<16;i++){
      int s = s0 + i;
      float xs = silu_f(xbase[(size_t)(t0+s)*DPROJP]);
      smX[p*68 + s] = xp_ + sLam[s]*(xs - xp_);
      xp_ = xs;
    }
  }
  __syncthreads();

  // ---- phase 2: GEMM1  S = C @ Beff^T (K=128), f16 ----
  int tq = w >> 1, sq = w & 1;
  f32x4 acc1[2][2] = {};
  #pragma unroll
  for (int kt=0; kt<4; kt++){
    f16x8 ah[2], bh[2];
    #pragma unroll
    for (int i=0;i<2;i++)
      ah[i] = fragH(smC + (tq*32 + i*16 + fr)*132 + kt*32 + kq*8);
    #pragma unroll
    for (int j=0;j<2;j++)
      bh[j] = fragH(smB + (sq*32 + j*16 + fr)*132 + kt*32 + kq*8);
    #pragma unroll
    for (int i=0;i<2;i++)
      #pragma unroll
      for (int j=0;j<2;j++)
        acc1[i][j] = __builtin_amdgcn_mfma_f32_16x16x32_f16(ah[i], bh[j], acc1[i][j], 0,0,0);
  }
  // mask: S'[t,s] = S * exp2(cl_t - cl_s) * dt_s for s<=t else 0
  #pragma unroll
  for (int i=0;i<2;i++){
    int tb = tq*32 + i*16 + kq*4;
    f32x4 clt = *(const f32x4*)&sCl[tb];
    #pragma unroll
    for (int j=0;j<2;j++){
      int scol = sq*32 + j*16 + fr;
      float cls = sCl[scol], dts = sDt[scol];
      #pragma unroll
      for (int q=0;q<4;q++){
        float m = (tb+q >= scol) ? exp2f(clt[q]-cls)*dts : 0.f;
        acc1[i][j][q] *= m;
      }
    }
  }
  __syncthreads();                // all GEMM1 LDS reads finished
  #pragma unroll
  for (int i=0;i<2;i++){
    int tb = tq*32 + i*16 + kq*4;
    #pragma unroll
    for (int j=0;j<2;j++){
      int scol = sq*32 + j*16 + fr;
      #pragma unroll
      for (int q=0;q<4;q++)
        sSp[(tb+q)*68 + scol] = acc1[i][j][q];
    }
  }
  __syncthreads();

  float Dh = Dp[h];
  // ---- phase 3: GEMM2  Y = S' @ Xe  (K=64) + D*xe, write slice0 ----
  {
    f32x4 acc2[2][2] = {};
    #pragma unroll
    for (int kt=0; kt<2; kt++){
      f16x8 ah[2], bh[2];
      #pragma unroll
      for (int i=0;i<2;i++)
        ah[i] = fragH(sSp + (tq*32 + i*16 + fr)*68 + kt*32 + kq*8);
      #pragma unroll
      for (int j=0;j<2;j++)
        bh[j] = fragH(smX + (sq*32 + j*16 + fr)*68 + kt*32 + kq*8);
      #pragma unroll
      for (int i=0;i<2;i++)
        #pragma unroll
        for (int j=0;j<2;j++)
          acc2[i][j] = __builtin_amdgcn_mfma_f32_16x16x32_f16(ah[i], bh[j], acc2[i][j], 0,0,0);
    }
    #pragma unroll
    for (int i=0;i<2;i++){
      int tb = tq*32 + i*16 + kq*4;
      #pragma unroll
      for (int j=0;j<2;j++){
        int pc = sq*32 + j*16 + fr;
        #pragma unroll
        for (int q=0;q<4;q++){
          float y = acc2[i][j][q] + Dh * smX[pc*68 + tb + q];
          ypart[(size_t)(t0+tb+q)*DSSM + h*64 + pc] = y;
        }
      }
    }
  }

  // ---- phase 4: GEMM4  H_local = Xe @ (w-scaled B)^T  (K=64) ----
  {
    f32x4 acc4[2][4] = {};
    int ph = w >> 1, dh = w & 1;
    #pragma unroll
    for (int kt=0; kt<2; kt++){
      f16x8 ah[2], bh[4];
      #pragma unroll
      for (int i=0;i<2;i++)
        ah[i] = fragH(smX + (ph*32 + i*16 + fr)*68 + kt*32 + kq*8);
      #pragma unroll
      for (int j=0;j<4;j++)
        bh[j] = fragH(smBT + (dh*64 + j*16 + fr)*68 + kt*32 + kq*8);
      #pragma unroll
      for (int i=0;i<2;i++)
        #pragma unroll
        for (int j=0;j<4;j++)
          acc4[i][j] = __builtin_amdgcn_mfma_f32_16x16x32_f16(ah[i], bh[j], acc4[i][j], 0,0,0);
    }
    size_t hb = (size_t)idx * 64 * 128;
    #pragma unroll
    for (int i=0;i<2;i++){
      int pb = ph*32 + i*16 + kq*4;
      #pragma unroll
      for (int j=0;j<4;j++){
        int dc = dh*64 + j*16 + fr;
        #pragma unroll
        for (int q=0;q<4;q++)
          hcarry[hb + (size_t)(pb+q)*128 + dc] = acc4[i][j][q];
      }
    }
  }
}

// ------------- pass 2: propagate carries across chunks -------------
__global__ __launch_bounds__(256) void scan2_kernel(float* __restrict__ hcarry,
    const float* __restrict__ AtotB)
{
  int idx = blockIdx.x*256 + threadIdx.x;
  int d = idx & 127, pp = (idx >> 7) & 63, h = (idx >> 13) & 31, b = idx >> 18;
  size_t base = ((size_t)(b*32+h)*512 + pp)*128 + d;
  float Hin = 0.f;
  #pragma unroll
  for (int c=0; c<NCH; c++){
    float Atot = AtotB[(b*32+h)*8 + c];
    float S = hcarry[base + (size_t)c*8192];
    hcarry[base + (size_t)c*8192] = Hin;
    Hin = Atot*Hin + S;
  }
}

// ------------- pass 3: Y2 = exp2(cl_t) * C @ Hin^T  (K=128), write slice1 -------------
__global__ __launch_bounds__(256) void scanB_kernel(
    const float* __restrict__ Cg, const float* __restrict__ hcarry,
    const float* __restrict__ clog, float* __restrict__ ypart)
{
  __shared__ __align__(16) float smC[64*132];
  __shared__ __align__(16) float smH[64*132];   // Hin [p][d]
  __shared__ __align__(16) float sK[64];
  int blk = blockIdx.x;
  int c = blk & 7, h = (blk>>3)&31, b = blk>>8;
  int idx = blk;
  int t0 = b*LSEQ + c*CL;
  int tid = threadIdx.x;
  int w = tid >> 6, lane = tid & 63;
  int fr = lane & 15, kq = lane >> 4;
  {
    int s = tid >> 2, dq4 = (tid & 3) * 32;
    const float* src = Cg + (size_t)(t0+s)*128 + dq4;
    float* dst = smC + s*132 + dq4;
    #pragma unroll
    for (int i=0;i<8;i++) *(f32x4*)(dst + i*4) = *(const f32x4*)(src + i*4);
    const float* hs = hcarry + (size_t)idx*8192 + (size_t)s*128 + dq4;
    float* hd = smH + s*132 + dq4;
    #pragma unroll
    for (int i=0;i<8;i++) *(f32x4*)(hd + i*4) = *(const f32x4*)(hs + i*4);
  }
  if (tid < 64) sK[tid] = exp2f(clog[(size_t)idx*64 + tid]);
  __syncthreads();

  int tq = w >> 1, pq = w & 1;
  f32x4 acc[2][2] = {};
  #pragma unroll
  for (int kt=0; kt<4; kt++){
    f16x8 ah[2], bh[2];
    #pragma unroll
    for (int i=0;i<2;i++)
      ah[i] = fragH(smC + (tq*32 + i*16 + fr)*132 + kt*32 + kq*8);
    #pragma unroll
    for (int j=0;j<2;j++)
      bh[j] = fragH(smH + (pq*32 + j*16 + fr)*132 + kt*32 + kq*8);
    #pragma unroll
    for (int i=0;i<2;i++)
      #pragma unroll
      for (int j=0;j<2;j++)
        acc[i][j] = __builtin_amdgcn_mfma_f32_16x16x32_f16(ah[i], bh[j], acc[i][j], 0,0,0);
  }
  #pragma unroll
  for (int i=0;i<2;i++){
    int tb = tq*32 + i*16 + kq*4;
    f32x4 kv = *(const f32x4*)&sK[tb];
    #pragma unroll
    for (int j=0;j<2;j++){
      int pc = pq*32 + j*16 + fr;
      #pragma unroll
      for (int q=0;q<4;q++)
        ypart[(size_t)TOK*DSSM + (size_t)(t0+tb+q)*DSSM + h*64 + pc] = acc[i][j][q]*kv[q];
    }
  }
}

// ------------- final: sum 2 partials, *silu(z), rms*norm_w -> f16 -------------
__global__ __launch_bounds__(256) void fin_kernel(const float* __restrict__ zx,
    const float* __restrict__ ypart, const float* __restrict__ normw,
    f16* __restrict__ yf)
{
  int t = blockIdx.x; int tid = threadIdx.x;
  __shared__ float red[256];
  float vloc[8];
  float ss = 0.f;
  #pragma unroll
  for (int i=0;i<8;i++){
    int cc = tid + i*256;
    float y = ypart[(size_t)t*DSSM + cc]
            + ypart[(size_t)(TOK + t)*DSSM + cc];
    float z = zx[(size_t)t*DPROJP + cc];
    float v = y * (z / (1.f + expf(-z)));
    vloc[i] = v; ss += v*v;
  }
  red[tid] = ss; __syncthreads();
  #pragma unroll
  for (int s=128; s>0; s>>=1){ if (tid < s) red[tid] += red[tid+s]; __syncthreads(); }
  float rs = rsqrtf(red[0]*(1.f/2048.f) + 1e-5f);
  #pragma unroll
  for (int i=0;i<8;i++){
    int cc = tid + i*256;
    yf[(size_t)t*DSSM + cc] = (f16)(vloc[i]*rs*normw[cc]);
  }
}

extern "C" void kernel_launch(void* const* d_in, const int* in_sizes, int n_in,
                              void* d_out, int out_size, void* d_ws, size_t ws_size,
                              hipStream_t stream)
{
  const float* u      = (const float*)d_in[0];
  const float* W_in   = (const float*)d_in[1];
  const float* W_out  = (const float*)d_in[2];
  const float* dt_bias= (const float*)d_in[3];
  const float* A_log  = (const float*)d_in[4];
  const float* Dp     = (const float*)d_in[5];
  const float* B_bias = (const float*)d_in[6];
  const float* C_bias = (const float*)d_in[7];
  const float* Bnw    = (const float*)d_in[8];
  const float* Cnw    = (const float*)d_in[9];
  const float* normw  = (const float*)d_in[10];
  float* out = (float*)d_out;

  char* ws = (char*)d_ws;
  size_t o = 0;
  auto alloc = [&](size_t bytes)->char*{
    char* r = ws + o; o = (o + bytes + 255) & ~(size_t)255; return r;
  };
  f16*  WT   = (f16*)alloc((size_t)DPROJP*DMODEL*2);
  f16*  WoT  = (f16*)alloc((size_t)DMODEL*DSSM*2);
  f16*  uhf  = (f16*)alloc((size_t)TOK*DMODEL*2);
  f16*  yf   = (f16*)alloc((size_t)TOK*DSSM*2);
  float*  zx   = (float*)alloc((size_t)TOK*DPROJP*4);
  float*  thT  = (float*)alloc((size_t)2*2048*512*4);
  float*  cosm = (float*)alloc((size_t)2*TOK*64*4);
  float*  sinm = (float*)alloc((size_t)2*TOK*64*4);
  float*  Bgb  = (float*)alloc((size_t)TOK*128*4);
  float*  Cgb  = (float*)alloc((size_t)TOK*128*4);
  float4* scal = (float4*)alloc((size_t)TOK*32*16);
  float*  ypart= (float*)alloc((size_t)2*TOK*DSSM*4);
  float*  hcarry=(float*)alloc((size_t)2*32*NCH*64*128*4);
  float*  clog = (float*)alloc((size_t)512*64*4);
  float*  AtotB= (float*)alloc((size_t)512*4);
  float*  Cpart =(float*)alloc((size_t)4*TOK*DMODEL*4);

  // weights -> transposed f16; u -> f16
  transqh_kernel<<<dim3(DPROJP/32, DMODEL/32), dim3(256), 0, stream>>>(W_in, WT, DMODEL, DPROJ);
  transqh_kernel<<<dim3(DMODEL/32, DSSM/32),   dim3(256), 0, stream>>>(W_out, WoT, DSSM, DMODEL);
  cvtH_kernel<<<dim3(TOK*DMODEL/1024), dim3(256), 0, stream>>>(u, uhf);

  // in-proj: zx = u @ W_in  (M=1024, N=6528, K=1024), 408 blocks
  gemmh_kernel<<<dim3(408), dim3(256), 0, stream>>>(uhf, WT, zx, DMODEL, DMODEL, DPROJP, 51, 51);

  // theta transpose + cumsum + cos/sin (256 blocks, 16 heads each)
  thT_kernel<<<dim3(32, 8, 2), dim3(256), 0, stream>>>(zx, thT);
  cum2_kernel<<<dim3(256), dim3(512), 0, stream>>>(thT, cosm, sinm);

  // per-token elementwise
  ew_kernel<<<dim3(TOK), dim3(256), 0, stream>>>(zx, cosm, sinm, dt_bias, A_log,
                                                 B_bias, C_bias, Bnw, Cnw, Bgb, Cgb, scal);

  // attention-form chunked scan
  scanA_kernel<<<dim3(512),  dim3(256), 0, stream>>>(zx, Bgb, Cgb, scal, A_log, Dp,
                                                     ypart, hcarry, clog, AtotB);
  scan2_kernel<<<dim3(2048), dim3(256), 0, stream>>>(hcarry, AtotB);
  scanB_kernel<<<dim3(512),  dim3(256), 0, stream>>>(Cgb, hcarry, clog, ypart);

  // gate + rms -> f16
  fin_kernel<<<dim3(TOK), dim3(256), 0, stream>>>(zx, ypart, normw, yf);

  // out-proj: split-K=4 (M=1024, N=1024, K=2048), 256 blocks
  gemmh_kernel<<<dim3(256), dim3(256), 0, stream>>>(yf, WoT, Cpart, DSSM, 512, DMODEL, 8, 32);
  red4_kernel<<<dim3(TOK*DMODEL/1024), dim3(256), 0, stream>>>(Cpart, out);
}